// Round 10
// baseline (540.033 us; speedup 1.0000x reference)
//
#include <hip/hip_runtime.h>
#include <math.h>

#define BSZ 4
#define LEN 2048
#define DM 1024
#define DI 2048
#define HD 64      // HEADDIM (p)
#define NH 32      // NHEADS
#define DS 128     // D_STATE (n)
#define CD 2304    // CONV_DIM
#define DP 4384    // D_IN_PROJ
#define NTOK (BSZ*LEN)   // 8192
#define QCH 128          // chunk length
#define NCH (LEN/QCH)    // 16 chunks
#define TOFF (DP-NH)     // 4352: dt raw cols in W_in

#define CONV_R 64
#define NRB (NTOK/CONV_R)
#define NPAD 4352        // z + xBC exactly (dt handled in fp32 path)

typedef unsigned short ushort_t;
typedef __bf16 bf16x8 __attribute__((ext_vector_type(8)));
typedef ushort_t us8 __attribute__((ext_vector_type(8)));
typedef float f32x4 __attribute__((ext_vector_type(4)));

__device__ __forceinline__ ushort_t f2bf(float f) {
    unsigned u = __float_as_uint(f);
    unsigned r = (u + 0x7FFFu + ((u >> 16) & 1u)) >> 16;
    return (ushort_t)r;
}
__device__ __forceinline__ float bf2f(ushort_t u) {
    return __uint_as_float(((unsigned)u) << 16);
}
__device__ __forceinline__ bf16x8 us2bf(us8 v) {
    union { us8 u; bf16x8 b; } x; x.u = v; return x.b;
}

__device__ __forceinline__ void gl_lds16(const void* g, void* l) {
    __builtin_amdgcn_global_load_lds(
        (const __attribute__((address_space(1))) void*)g,
        (__attribute__((address_space(3))) void*)l, 16, 0, 0);
}

// ---------------------------------------------------------------------------
// fp32 -> bf16 elementwise (hidden). 4 elems/thread.
// ---------------------------------------------------------------------------
__global__ __launch_bounds__(256) void cvt_bf16(
    const float* __restrict__ A, ushort_t* __restrict__ Ab)
{
    size_t i = ((size_t)blockIdx.x * 256 + threadIdx.x) * 4;
    float4 v = *(const float4*)(A + i);
    ushort_t o[4] = { f2bf(v.x), f2bf(v.y), f2bf(v.z), f2bf(v.w) };
    *(uint2*)(Ab + i) = *(uint2*)o;
}

// ---------------------------------------------------------------------------
// W[k][n] fp32 (ld=ldw) -> Wt[n][k] bf16 (ld=K), zero-pad for n >= N.
// Optional per-k column scale (used to fold norm_w into W_out).
// ---------------------------------------------------------------------------
__global__ __launch_bounds__(256) void transpose_cvt(
    const float* __restrict__ W, ushort_t* __restrict__ Wt,
    const float* __restrict__ colscale, int K, int N, int ldw)
{
    __shared__ float T[32][33];
    const int n0 = blockIdx.x * 32;
    const int k0 = blockIdx.y * 32;
    const int tid = threadIdx.x;
    #pragma unroll
    for (int l = 0; l < 4; l++) {
        int idx = tid + l * 256;
        int ki = idx >> 5, nj = idx & 31;
        int n = n0 + nj;
        float s = colscale ? colscale[k0 + ki] : 1.f;
        T[ki][nj] = (n < N) ? W[(size_t)(k0 + ki) * ldw + n] * s : 0.f;
    }
    __syncthreads();
    #pragma unroll
    for (int l = 0; l < 4; l++) {
        int idx = tid + l * 256;
        int nj = idx >> 5, ki = idx & 31;
        Wt[(size_t)(n0 + nj) * K + k0 + ki] = f2bf(T[ki][nj]);
    }
}

// ---------------------------------------------------------------------------
// 128x128 BK=32 bf16 MFMA GEMM, TRIPLE-buffered (48 KiB -> 3 blocks/CU).
// Depth-2 prefetch with counted vmcnt ladder 8/4/0; swizzle
// byte^=((row>>1)&3)<<4 (0 conflicts, r7/r8-verified). Parked local optimum
// for GEMM1 (~101 us, r8); now templated: OB=true bf16 out (GEMM1), OB=false
// fp32 out with FUSED RMS row scale rsqrt(ss/DI+eps) (GEMM2).
// Requires M,N%128==0, K%32==0, grid%8==0 for XCD swizzle.
// ---------------------------------------------------------------------------
template <bool OB>
__global__ __launch_bounds__(256, 3) void gemm_tb(
    const ushort_t* __restrict__ A, const ushort_t* __restrict__ Bt,
    void* __restrict__ Cp, const float* __restrict__ rowscale,
    int K, int lda, int ldb, int ldc)
{
    __shared__ __align__(16) ushort_t LA[3][128 * 32];
    __shared__ __align__(16) ushort_t LB[3][128 * 32];
    const int tid = threadIdx.x;
    int bid = blockIdx.y * gridDim.x + blockIdx.x;
    const int nwg = gridDim.x * gridDim.y;
    if (!(nwg & 7)) bid = (bid & 7) * (nwg >> 3) + (bid >> 3);   // XCD swizzle
    const int n0 = (bid % gridDim.x) * 128;
    const int m0 = (bid / gridDim.x) * 128;
    const int lane = tid & 63;
    const int w = tid >> 6;             // 0..3
    const int wm = w >> 1, wn = w & 1;  // 2 (M) x 2 (N) waves
    const int lm = lane & 15, quad = lane >> 4;
    const int ck = ((quad * 16) ^ (((lm >> 1) & 3) << 4)) >> 1;  // ushort col

    const int srow = tid >> 2;                      // 0..63
    const int scolb = ((tid & 3) * 16) ^ (((tid >> 3) & 3) << 4);
    const char* gA = (const char*)A + ((size_t)(m0 + srow) * lda) * 2 + scolb;
    const char* gB = (const char*)Bt + ((size_t)(n0 + srow) * ldb) * 2 + scolb;
    const size_t strA = (size_t)64 * lda * 2;
    const size_t strB = (size_t)64 * ldb * 2;
    const int ldst = tid * 8;   // ushort offset of this thread's 16B chunk

    f32x4 acc[4][4];
    #pragma unroll
    for (int i = 0; i < 4; i++)
        #pragma unroll
        for (int j = 0; j < 4; j++) acc[i][j] = (f32x4){0.f, 0.f, 0.f, 0.f};

    const int NTt = K >> 5;

    auto STAGE = [&](int kt1, int buf) {
        const char* a = gA + (size_t)kt1 * 64;    // 32 bf16 = 64 B per K-tile
        const char* b = gB + (size_t)kt1 * 64;
        gl_lds16(a + 0 * strA, &LA[buf][0 * 2048 + ldst]);
        gl_lds16(a + 1 * strA, &LA[buf][1 * 2048 + ldst]);
        gl_lds16(b + 0 * strB, &LB[buf][0 * 2048 + ldst]);
        gl_lds16(b + 1 * strB, &LB[buf][1 * 2048 + ldst]);
    };

    // prologue: tiles 0,1 in flight (depth 2)
    STAGE(0, 0);
    STAGE(1, 1);

    int cur = 0;        // buffer holding tile kt
    int sb  = 2;        // buffer to stage tile kt+2 into
    for (int kt = 0; kt < NTt; ++kt) {
        __builtin_amdgcn_s_barrier();
        const int ahead = NTt - 1 - kt;
        if (ahead >= 2) {
            STAGE(kt + 2, sb);
            asm volatile("s_waitcnt vmcnt(8)" ::: "memory"); // kt landed; kt+1,kt+2 fly
        } else if (ahead == 1) {
            asm volatile("s_waitcnt vmcnt(4)" ::: "memory"); // kt landed; kt+1 flies
        } else {
            asm volatile("s_waitcnt vmcnt(0)" ::: "memory");
        }
        __builtin_amdgcn_s_barrier();   // collective: tile kt fully in LDS

        bf16x8 af[4], bf[4];
        #pragma unroll
        for (int s = 0; s < 4; s++)
            af[s] = *(const bf16x8*)&LA[cur][((wm * 64 + s * 16 + lm) << 5) + ck];
        #pragma unroll
        for (int t = 0; t < 4; t++)
            bf[t] = *(const bf16x8*)&LB[cur][((wn * 64 + t * 16 + lm) << 5) + ck];
        __builtin_amdgcn_s_setprio(1);
        #pragma unroll
        for (int s = 0; s < 4; s++)
            #pragma unroll
            for (int t = 0; t < 4; t++)
                acc[s][t] = __builtin_amdgcn_mfma_f32_16x16x32_bf16(
                    af[s], bf[t], acc[s][t], 0, 0, 0);
        __builtin_amdgcn_s_setprio(0);

        cur = (cur == 2) ? 0 : cur + 1;
        sb  = (sb == 2) ? 0 : sb + 1;
    }

    #pragma unroll
    for (int s = 0; s < 4; s++) {
        const int row = m0 + wm * 64 + s * 16 + quad * 4;
        float rs[4] = {1.f, 1.f, 1.f, 1.f};
        if (!OB && rowscale) {
            #pragma unroll
            for (int r = 0; r < 4; r++)
                rs[r] = rsqrtf(rowscale[row + r] * (1.f / DI) + 1e-5f);
        }
        #pragma unroll
        for (int t = 0; t < 4; t++) {
            const int col = n0 + wn * 64 + t * 16 + lm;
            #pragma unroll
            for (int r = 0; r < 4; r++) {
                if (OB)
                    ((ushort_t*)Cp)[(size_t)(row + r) * ldc + col] = f2bf(acc[s][t][r]);
                else
                    ((float*)Cp)[(size_t)(row + r) * ldc + col] = acc[s][t][r] * rs[r];
            }
        }
    }
}

// ---------------------------------------------------------------------------
// Depthwise causal conv (w=4) + bias + SiLU -> bf16 operand caches.
// ---------------------------------------------------------------------------
__global__ __launch_bounds__(256) void conv_silu_bf16(
    const ushort_t* __restrict__ xbcb, const float* __restrict__ cw,
    const float* __restrict__ cb, ushort_t* __restrict__ xT,
    ushort_t* __restrict__ Bn, ushort_t* __restrict__ BT,
    ushort_t* __restrict__ Cn)
{
    __shared__ ushort_t Tl[256][68];
    const int tid = threadIdx.x;
    const int c = blockIdx.x * 256 + tid;
    const int rb = blockIdx.y;
    const int row0 = rb * CONV_R;
    const bool isBC = (blockIdx.x == 8);

    const float w0 = cw[c*4+0], w1 = cw[c*4+1], w2 = cw[c*4+2], w3 = cw[c*4+3];
    const float bias = cb[c];
    float h0 = 0.f, h1 = 0.f, h2 = 0.f;
    if ((row0 & (LEN - 1)) != 0) {
        h0 = bf2f(xbcb[(size_t)(row0 - 3) * NPAD + c]);
        h1 = bf2f(xbcb[(size_t)(row0 - 2) * NPAD + c]);
        h2 = bf2f(xbcb[(size_t)(row0 - 1) * NPAD + c]);
    }
    const ushort_t* p = xbcb + (size_t)row0 * NPAD + c;
    for (int r = 0; r < CONV_R; r++) {
        float xin = bf2f(*p);
        float a = bias + w0*h0 + w1*h1 + w2*h2 + w3*xin;
        ushort_t bv = f2bf(a / (1.f + __expf(-a)));
        Tl[tid][r] = bv;
        if (isBC) {
            int row = row0 + r;
            if (tid < DS) Bn[(size_t)row * DS + tid] = bv;
            else          Cn[(size_t)row * DS + (tid - DS)] = bv;
        }
        h0 = h1; h1 = h2; h2 = xin;
        p += NPAD;
    }
    __syncthreads();

    const int seg = tid & 7;
    const int clb = tid >> 3;
    if (!isBC) {
        #pragma unroll
        for (int pass = 0; pass < 8; pass++) {
            int cl = pass * 32 + clb;
            int cc = blockIdx.x * 256 + cl;
            us8 v;
            #pragma unroll
            for (int j = 0; j < 8; j++) v[j] = Tl[cl][seg * 8 + j];
            *(us8*)&xT[(size_t)cc * NTOK + row0 + seg * 8] = v;
        }
    } else {
        #pragma unroll
        for (int pass = 0; pass < 4; pass++) {
            int n = pass * 32 + clb;
            us8 v;
            #pragma unroll
            for (int j = 0; j < 8; j++) v[j] = Tl[n][seg * 8 + j];
            *(us8*)&BT[(size_t)n * NTOK + row0 + seg * 8] = v;
        }
    }
}

// ---------------------------------------------------------------------------
// Batched head-independent GEMM: Graw[bc][t][s] = sum_n C[t,n]*B[s,n].
// ---------------------------------------------------------------------------
__global__ __launch_bounds__(256) void gct_gemm(
    const ushort_t* __restrict__ Bn, const ushort_t* __restrict__ Cn,
    float* __restrict__ Graw)
{
    const int bc = blockIdx.x;             // b*NCH + chunk
    const int chunk = bc % NCH;
    const int b = bc / NCH;
    const size_t rowbase = (size_t)b * LEN + (size_t)chunk * QCH;
    const int tid = threadIdx.x;
    const int w = tid >> 6, lane = tid & 63;
    const int lm = lane & 15, quad = lane >> 4;
    const int tw0 = w * 32;

    f32x4 acc[2][8];
    #pragma unroll
    for (int ti = 0; ti < 2; ti++)
        #pragma unroll
        for (int sj = 0; sj < 8; sj++) acc[ti][sj] = (f32x4){0.f, 0.f, 0.f, 0.f};

    #pragma unroll
    for (int ks = 0; ks < 4; ks++) {
        const int k0 = ks * 32 + quad * 8;
        bf16x8 a0 = *(const bf16x8*)&Cn[(rowbase + tw0 + lm) * DS + k0];
        bf16x8 a1 = *(const bf16x8*)&Cn[(rowbase + tw0 + 16 + lm) * DS + k0];
        #pragma unroll
        for (int sj = 0; sj < 8; sj++) {
            bf16x8 bb = *(const bf16x8*)&Bn[(rowbase + sj * 16 + lm) * DS + k0];
            acc[0][sj] = __builtin_amdgcn_mfma_f32_16x16x32_bf16(a0, bb, acc[0][sj], 0, 0, 0);
            acc[1][sj] = __builtin_amdgcn_mfma_f32_16x16x32_bf16(a1, bb, acc[1][sj], 0, 0, 0);
        }
    }
    float* G = Graw + (size_t)bc * (QCH * QCH);
    #pragma unroll
    for (int ti = 0; ti < 2; ti++)
        #pragma unroll
        for (int sj = 0; sj < 8; sj++)
            #pragma unroll
            for (int r = 0; r < 4; r++)
                G[(size_t)(tw0 + ti * 16 + quad * 4 + r) * QCH + sj * 16 + lm] = acc[ti][sj][r];
}

// ---------------------------------------------------------------------------
// dt in FULL fp32 straight from hidden @ W_in[:, TOFF:] (exp-amplified path).
// ---------------------------------------------------------------------------
__global__ __launch_bounds__(256) void dt_proc_fp32(
    const float* __restrict__ hidden, const float* __restrict__ W_in,
    const float* __restrict__ dt_bias, const float* __restrict__ A_log,
    float* __restrict__ dtv, float* __restrict__ ldA)
{
    const int h = threadIdx.x & 31;
    const int tt = threadIdx.x >> 5;
    const int t = blockIdx.x * 8 + tt;
    const float* hr = hidden + (size_t)t * DM;
    const float* wc = W_in + TOFF + h;
    float a0 = 0.f, a1 = 0.f, a2 = 0.f, a3 = 0.f;
    for (int k = 0; k < DM; k += 4) {
        a0 += hr[k+0] * wc[(size_t)(k+0) * DP];
        a1 += hr[k+1] * wc[(size_t)(k+1) * DP];
        a2 += hr[k+2] * wc[(size_t)(k+2) * DP];
        a3 += hr[k+3] * wc[(size_t)(k+3) * DP];
    }
    float v = (a0 + a1) + (a2 + a3) + dt_bias[h];
    float sp = (v > 20.f) ? v : log1pf(expf(v));
    int idx = t * NH + h;
    dtv[idx] = sp;
    ldA[idx] = -sp * expf(A_log[h]);
}

// ---------------------------------------------------------------------------
// Per-(b,h,chunk) prefix scan of ldA (one wave per block, shfl-based).
// ---------------------------------------------------------------------------
__global__ __launch_bounds__(64) void scan_chunk(
    const float* __restrict__ dtv, const float* __restrict__ ldA,
    float* __restrict__ lcpb, float* __restrict__ dtsb,
    float* __restrict__ coefb, float* __restrict__ csum)
{
    const int blk = blockIdx.x;            // bh*NCH + chunk
    const int chunk = blk % NCH;
    const int bh = blk / NCH;
    const int h = bh % NH;
    const int b = bh / NH;
    const int lane = threadIdx.x;
    const size_t rowbase = (size_t)b * LEN + (size_t)chunk * QCH;
    const int t0 = 2 * lane, t1 = 2 * lane + 1;
    float v0 = ldA[(rowbase + t0) * NH + h];
    float v1 = ldA[(rowbase + t1) * NH + h];
    float d0 = dtv[(rowbase + t0) * NH + h];
    float d1 = dtv[(rowbase + t1) * NH + h];
    float pair = v0 + v1;
    #pragma unroll
    for (int off = 1; off < 64; off <<= 1) {
        float n = __shfl_up(pair, off, 64);
        if (lane >= off) pair += n;
    }
    float l1 = pair, l0 = pair - v1;
    float total = __shfl(pair, 63, 64);
    size_t base = (size_t)blk * QCH;
    *(float2*)&lcpb[base + t0] = make_float2(l0, l1);
    *(float2*)&dtsb[base + t0] = make_float2(d0, d1);
    *(float2*)&coefb[base + t0] =
        make_float2(__expf(total - l0) * d0, __expf(total - l1) * d1);
    if (lane == 63) csum[blk] = total;
}

// ---------------------------------------------------------------------------
// FUSED Phase 1+2, parallelism-fixed (r9's was 1 wave/SIMD, latency-exposed).
// Grid = (bh * 8 n-tiles) = 1024 blocks (4/CU, 16 waves/CU); wave w = p-tile.
// Per (p-tile, n-tile) wave, loop chunks c=0..15:
//   acc[p][n] = sum_s (coef_s*x[s,p])*B[s,n]  (1 MFMA/ks, same k-order)
//   hsb[c] = f2bf(run); run = exp(csum[c])*run + acc   (identical numerics)
// Recurrence is elementwise per (p,n) -> waves fully independent.
// ---------------------------------------------------------------------------
__global__ __launch_bounds__(256) void phase12_fused(
    const ushort_t* __restrict__ xT, const ushort_t* __restrict__ BT,
    const float* __restrict__ coefb, const float* __restrict__ csum,
    ushort_t* __restrict__ hsb)
{
    const int blk = blockIdx.x;            // bh*8 + nt
    const int nt = blk & 7;
    const int bh = blk >> 3;
    const int h = bh & (NH - 1);
    const int b = bh >> 5;
    const int tid = threadIdx.x;
    const int w = tid >> 6, lane = tid & 63;   // w = p-tile index (0..3)
    const int lm = lane & 15, quad = lane >> 4;
    const int nw0 = nt * 16;

    f32x4 run = (f32x4){0.f, 0.f, 0.f, 0.f};

    for (int c = 0; c < NCH; c++) {
        const size_t rowbase = (size_t)b * LEN + (size_t)c * QCH;
        const size_t cb = ((size_t)bh * NCH + c) * QCH;
        const float P = __expf(csum[bh * NCH + c]);

        f32x4 acc = (f32x4){0.f, 0.f, 0.f, 0.f};
        #pragma unroll
        for (int ks = 0; ks < 4; ks++) {
            const int k0 = ks * 32 + quad * 8;
            bf16x8 a = *(const bf16x8*)&xT[(size_t)(h * HD + w * 16 + lm) * NTOK + rowbase + k0];
            float4 c0 = *(const float4*)&coefb[cb + k0];
            float4 c1 = *(const float4*)&coefb[cb + k0 + 4];
            float cf[8] = { c0.x, c0.y, c0.z, c0.w, c1.x, c1.y, c1.z, c1.w };
            us8 raw = *(const us8*)&BT[(size_t)(nw0 + lm) * NTOK + rowbase + k0];
            us8 sb;
            #pragma unroll
            for (int j = 0; j < 8; j++) sb[j] = f2bf(bf2f(raw[j]) * cf[j]);
            acc = __builtin_amdgcn_mfma_f32_16x16x32_bf16(a, us2bf(sb), acc, 0, 0, 0);
        }

        // write h_start (pre-update run), then recurrence update
        ushort_t* hb = hsb + ((size_t)bh * NCH + c) * (HD * DS);
        #pragma unroll
        for (int r = 0; r < 4; r++)
            hb[(size_t)(w * 16 + quad * 4 + r) * DS + nw0 + lm] = f2bf(run[r]);
        #pragma unroll
        for (int r = 0; r < 4; r++)
            run[r] = P * run[r] + acc[r];
    }
}

// ---------------------------------------------------------------------------
// Phase 3 (MFMA) + FUSED GATE: Y = G@X + Chat@hs^T; epilogue adds D*x,
// multiplies silu(z) (gate), writes gated bf16 v into zxb's dead xBC slice
// (cols DI.., ld=NPAD) and accumulates per-token sum(v^2) via atomics.
// ---------------------------------------------------------------------------
__global__ __launch_bounds__(256) void phase3_mfma(
    const ushort_t* __restrict__ xT, const ushort_t* __restrict__ Cn,
    const ushort_t* __restrict__ hsb, const float* __restrict__ Graw,
    const float* __restrict__ lcpb, const float* __restrict__ dtsb,
    const float* __restrict__ Dvec, ushort_t* __restrict__ zxb,
    float* __restrict__ ss)
{
    const int tid = threadIdx.x;
    const int h = blockIdx.x & (NH - 1);
    const int bc = blockIdx.x >> 5;        // b*NCH + chunk
    const int chunk = bc % NCH;
    const int b = bc / NCH;
    const int blko = (b * NH + h) * NCH + chunk;
    const size_t rowbase = (size_t)b * LEN + (size_t)chunk * QCH;

    __shared__ float lcp[QCH];
    __shared__ float dts[QCH];
    if (tid < QCH) {
        lcp[tid] = lcpb[(size_t)blko * QCH + tid];
        dts[tid] = dtsb[(size_t)blko * QCH + tid];
    }
    __syncthreads();

    const int w = tid >> 6, lane = tid & 63;
    const int lm = lane & 15, quad = lane >> 4;
    const int tw0 = w * 32;

    const float* Gr = Graw + (size_t)bc * (QCH * QCH);
    const ushort_t* hsp = hsb + (size_t)blko * (HD * DS);

    f32x4 acc2[2][4];
    #pragma unroll
    for (int ti = 0; ti < 2; ti++)
        #pragma unroll
        for (int pi = 0; pi < 4; pi++) acc2[ti][pi] = (f32x4){0.f, 0.f, 0.f, 0.f};

    #pragma unroll
    for (int ks = 0; ks < 8; ks++) {
        bf16x8 a[2], bb[4];
        if (ks < 4) {
            const int k0 = ks * 32 + quad * 8;
            #pragma unroll
            for (int ti = 0; ti < 2; ti++) {
                int t = tw0 + ti * 16 + lm;
                float lt = lcp[t];
                const float* gp = Gr + (size_t)t * QCH + k0;
                float4 g0 = *(const float4*)gp;
                float4 g1 = *(const float4*)(gp + 4);
                float ge[8] = { g0.x, g0.y, g0.z, g0.w, g1.x, g1.y, g1.z, g1.w };
                us8 sb;
                #pragma unroll
                for (int j = 0; j < 8; j++) {
                    int s = k0 + j;
                    float wv = (s <= t) ? (__expf(lt - lcp[s]) * dts[s]) : 0.f;
                    sb[j] = f2bf(ge[j] * wv);
                }
                a[ti] = us2bf(sb);
            }
            #pragma unroll
            for (int pi = 0; pi < 4; pi++)
                bb[pi] = *(const bf16x8*)&xT[(size_t)(h * HD + pi * 16 + lm) * NTOK + rowbase + k0];
        } else {
            const int k0 = (ks - 4) * 32 + quad * 8;
            #pragma unroll
            for (int ti = 0; ti < 2; ti++) {
                int t = tw0 + ti * 16 + lm;
                float sc = __expf(lcp[t]);
                us8 raw = *(const us8*)&Cn[(rowbase + t) * DS + k0];
                us8 sb;
                #pragma unroll
                for (int j = 0; j < 8; j++) sb[j] = f2bf(bf2f(raw[j]) * sc);
                a[ti] = us2bf(sb);
            }
            #pragma unroll
            for (int pi = 0; pi < 4; pi++)
                bb[pi] = *(const bf16x8*)&hsp[(size_t)(pi * 16 + lm) * DS + k0];
        }
        __builtin_amdgcn_s_setprio(1);
        #pragma unroll
        for (int ti = 0; ti < 2; ti++)
            #pragma unroll
            for (int pi = 0; pi < 4; pi++)
                acc2[ti][pi] = __builtin_amdgcn_mfma_f32_16x16x32_bf16(a[ti], bb[pi], acc2[ti][pi], 0, 0, 0);
        __builtin_amdgcn_s_setprio(0);
    }

    const float Dh = Dvec[h];
    float vsq[2][4] = {};
    #pragma unroll
    for (int ti = 0; ti < 2; ti++)
        #pragma unroll
        for (int pi = 0; pi < 4; pi++) {
            int tb = tw0 + ti * 16 + quad * 4;
            int col = h * HD + pi * 16 + lm;
            ushort4 xv = *(const ushort4*)&xT[(size_t)(h * HD + pi * 16 + lm) * NTOK + rowbase + tb];
            const ushort_t* xe = (const ushort_t*)&xv;
            #pragma unroll
            for (int r = 0; r < 4; r++) {
                size_t grow = rowbase + tb + r;
                float y = acc2[ti][pi][r] + Dh * bf2f(xe[r]);
                float z = bf2f(zxb[grow * NPAD + col]);
                float v = y * (z / (1.f + __expf(-z)));
                vsq[ti][r] += v * v;
                zxb[grow * NPAD + DI + col] = f2bf(v);
            }
        }
    #pragma unroll
    for (int ti = 0; ti < 2; ti++)
        #pragma unroll
        for (int r = 0; r < 4; r++) {
            float s = vsq[ti][r];
            s += __shfl_xor(s, 1, 64);
            s += __shfl_xor(s, 2, 64);
            s += __shfl_xor(s, 4, 64);
            s += __shfl_xor(s, 8, 64);
            if (lm == 0) {
                int tb = tw0 + ti * 16 + quad * 4 + r;
                atomicAdd(&ss[rowbase + tb], s);
            }
        }
}

// ---------------------------------------------------------------------------
extern "C" void kernel_launch(void* const* d_in, const int* in_sizes, int n_in,
                              void* d_out, int out_size, void* d_ws, size_t ws_size,
                              hipStream_t stream)
{
    const float* hidden  = (const float*)d_in[0];
    const float* W_in    = (const float*)d_in[1];
    const float* conv_w  = (const float*)d_in[2];
    const float* conv_b  = (const float*)d_in[3];
    const float* dt_bias = (const float*)d_in[4];
    const float* A_log   = (const float*)d_in[5];
    const float* Dv      = (const float*)d_in[6];
    const float* norm_w  = (const float*)d_in[7];
    const float* W_out   = (const float*)d_in[8];
    float* out = (float*)d_out;

    char* ws = (char*)d_ws;
    size_t o = 0;
    ushort_t* zxb  = (ushort_t*)(ws + o); o += (size_t)NTOK * NPAD * 2;             // 71.3 MB
    float* S       = (float*)(ws + o);    o += (size_t)BSZ * NH * NCH * HD * DS * 4;// 67.1 MB (Ah/W1t alias region)
    ushort_t* xT   = (ushort_t*)(ws + o); o += (size_t)DI * NTOK * 2;               // 33.6 MB
    ushort_t* Bn   = (ushort_t*)(ws + o); o += (size_t)NTOK * DS * 2;               // 2.1 MB
    ushort_t* BT   = (ushort_t*)(ws + o); o += (size_t)DS * NTOK * 2;               // 2.1 MB
    ushort_t* Cn   = (ushort_t*)(ws + o); o += (size_t)NTOK * DS * 2;               // 2.1 MB
    ushort_t* hsb  = (ushort_t*)(ws + o); o += (size_t)BSZ * NH * NCH * HD * DS * 2;// 33.6 MB
    float* Graw    = (float*)(ws + o);    o += (size_t)BSZ * NCH * QCH * QCH * 4;   // 4.2 MB
    float* dtv     = (float*)(ws + o);    o += (size_t)NTOK * NH * 4;
    float* ldA     = (float*)(ws + o);    o += (size_t)NTOK * NH * 4;
    float* lcpb    = (float*)(ws + o);    o += (size_t)BSZ * NH * LEN * 4;
    float* dtsb    = (float*)(ws + o);    o += (size_t)BSZ * NH * LEN * 4;
    float* coefb   = (float*)(ws + o);    o += (size_t)BSZ * NH * LEN * 4;
    float* csum    = (float*)(ws + o);    o += (size_t)BSZ * NH * NCH * 4;
    float* ss      = (float*)(ws + o);    o += (size_t)NTOK * 4;
    (void)S;
    // Aliases (dead-region reuse):
    ushort_t* Ah   = (ushort_t*)S;                                   // GEMM1 A (bf16 hidden)
    ushort_t* W1t  = (ushort_t*)((char*)S + (size_t)NTOK * DM * 2);  // GEMM1 B^T
    ushort_t* Wot  = hsb;                                            // post-phase3 (hsb dead)
    ushort_t* xbcb = zxb + DI;                                       // xBC slice, ld=NPAD
    ushort_t* ynb  = zxb + DI;                                       // gated-v slice (post-conv), ld=NPAD

    // 0) zero the sum-of-squares accumulator (consumed by phase3 atomics)
    hipMemsetAsync(ss, 0, (size_t)NTOK * 4, stream);
    // 1) bf16 conversions for GEMM1
    cvt_bf16<<<(NTOK * DM) / 1024, 256, 0, stream>>>(hidden, Ah);
    transpose_cvt<<<dim3(NPAD / 32, DM / 32), 256, 0, stream>>>(
        W_in, W1t, nullptr, DM, NPAD, DP);
    // 2) GEMM1 (merged z + xBC, bf16 out) — triple-buffered depth-2 prefetch
    gemm_tb<true><<<dim3(NPAD / 128, NTOK / 128), 256, 0, stream>>>(
        Ah, W1t, zxb, nullptr, DM, DM, DM, NPAD);
    // 3) conv + SiLU -> bf16 operand caches
    conv_silu_bf16<<<dim3(CD / 256, NRB), 256, 0, stream>>>(
        xbcb, conv_w, conv_b, xT, Bn, BT, Cn);
    // 4) head-shared C.B^T (once per (b,chunk))
    gct_gemm<<<BSZ * NCH, 256, 0, stream>>>(Bn, Cn, Graw);
    // 5) dt in fp32 + hoisted per-chunk prefix scan
    dt_proc_fp32<<<NTOK / 8, 256, 0, stream>>>(hidden, W_in, dt_bias, A_log, dtv, ldA);
    scan_chunk<<<BSZ * NH * NCH, 64, 0, stream>>>(dtv, ldA, lcpb, dtsb, coefb, csum);
    // 6+7) FUSED chunk states + cross-chunk recurrence -> bf16 h_start.
    //      1024 blocks = 4/CU (was 1/CU = 1 wave/SIMD latency-exposed).
    phase12_fused<<<BSZ * NH * 8, 256, 0, stream>>>(xT, BT, coefb, csum, hsb);
    // 8) per-chunk outputs + fused gate -> gated bf16 v into zxb xBC slice,
    //    per-token sum(v^2) via atomics
    phase3_mfma<<<BSZ * NH * NCH, 256, 0, stream>>>(
        xT, Cn, hsb, Graw, lcpb, dtsb, Dv, zxb, ss);
    // 9) W_out transpose (hsb dead) with norm_w folded in, then
    //    out = (v @ diag(nw) W_out) * rsqrt(ss/DI+eps)  (RMS fused in epilogue)
    transpose_cvt<<<dim3(DM / 32, DI / 32), 256, 0, stream>>>(
        W_out, Wot, norm_w, DI, DM, DM);
    gemm_tb<false><<<dim3(DM / 128, NTOK / 128), 256, 0, stream>>>(
        ynb, Wot, out, ss, DI, NPAD, DI, DM);
}

// Round 11
// 516.808 us; speedup vs baseline: 1.0449x; 1.0449x over previous
//
#include <hip/hip_runtime.h>
#include <math.h>

#define BSZ 4
#define LEN 2048
#define DM 1024
#define DI 2048
#define HD 64      // HEADDIM (p)
#define NH 32      // NHEADS
#define DS 128     // D_STATE (n)
#define CD 2304    // CONV_DIM
#define DP 4384    // D_IN_PROJ
#define NTOK (BSZ*LEN)   // 8192
#define QCH 128          // chunk length
#define NCH (LEN/QCH)    // 16 chunks
#define TOFF (DP-NH)     // 4352: dt raw cols in W_in

#define CONV_R 64
#define NRB (NTOK/CONV_R)
#define NPAD 4352        // z + xBC exactly (dt handled in fp32 path)

typedef unsigned short ushort_t;
typedef __bf16 bf16x8 __attribute__((ext_vector_type(8)));
typedef ushort_t us8 __attribute__((ext_vector_type(8)));
typedef float f32x4 __attribute__((ext_vector_type(4)));

__device__ __forceinline__ ushort_t f2bf(float f) {
    unsigned u = __float_as_uint(f);
    unsigned r = (u + 0x7FFFu + ((u >> 16) & 1u)) >> 16;
    return (ushort_t)r;
}
__device__ __forceinline__ float bf2f(ushort_t u) {
    return __uint_as_float(((unsigned)u) << 16);
}
__device__ __forceinline__ bf16x8 us2bf(us8 v) {
    union { us8 u; bf16x8 b; } x; x.u = v; return x.b;
}

__device__ __forceinline__ void gl_lds16(const void* g, void* l) {
    __builtin_amdgcn_global_load_lds(
        (const __attribute__((address_space(1))) void*)g,
        (__attribute__((address_space(3))) void*)l, 16, 0, 0);
}

// ---------------------------------------------------------------------------
// fp32 -> bf16 elementwise (hidden). 4 elems/thread.
// ---------------------------------------------------------------------------
__global__ __launch_bounds__(256) void cvt_bf16(
    const float* __restrict__ A, ushort_t* __restrict__ Ab)
{
    size_t i = ((size_t)blockIdx.x * 256 + threadIdx.x) * 4;
    float4 v = *(const float4*)(A + i);
    ushort_t o[4] = { f2bf(v.x), f2bf(v.y), f2bf(v.z), f2bf(v.w) };
    *(uint2*)(Ab + i) = *(uint2*)o;
}

// ---------------------------------------------------------------------------
// W[k][n] fp32 (ld=ldw) -> Wt[n][k] bf16 (ld=K), zero-pad for n >= N.
// Optional per-k column scale (used to fold norm_w into W_out).
// ---------------------------------------------------------------------------
__global__ __launch_bounds__(256) void transpose_cvt(
    const float* __restrict__ W, ushort_t* __restrict__ Wt,
    const float* __restrict__ colscale, int K, int N, int ldw)
{
    __shared__ float T[32][33];
    const int n0 = blockIdx.x * 32;
    const int k0 = blockIdx.y * 32;
    const int tid = threadIdx.x;
    #pragma unroll
    for (int l = 0; l < 4; l++) {
        int idx = tid + l * 256;
        int ki = idx >> 5, nj = idx & 31;
        int n = n0 + nj;
        float s = colscale ? colscale[k0 + ki] : 1.f;
        T[ki][nj] = (n < N) ? W[(size_t)(k0 + ki) * ldw + n] * s : 0.f;
    }
    __syncthreads();
    #pragma unroll
    for (int l = 0; l < 4; l++) {
        int idx = tid + l * 256;
        int nj = idx >> 5, ki = idx & 31;
        Wt[(size_t)(n0 + nj) * K + k0 + ki] = f2bf(T[ki][nj]);
    }
}

// ---------------------------------------------------------------------------
// GEMM1: 128x128 BK=32, TRIPLE-buffered (48 KiB -> 3 blocks/CU). Depth-2
// prefetch with counted vmcnt ladder 8/4/0; swizzle byte^=((row>>1)&3)<<4
// (0 conflicts). Parked local optimum (~101 us full-M, r8). Launched as TWO
// M-half dispatches (diagnostic: lets sub-51us kernels surface in top-5).
// ---------------------------------------------------------------------------
__global__ __launch_bounds__(256, 3) void gemm1_tb(
    const ushort_t* __restrict__ A, const ushort_t* __restrict__ Bt,
    ushort_t* __restrict__ C, int K, int lda, int ldb, int ldc)
{
    __shared__ __align__(16) ushort_t LA[3][128 * 32];
    __shared__ __align__(16) ushort_t LB[3][128 * 32];
    const int tid = threadIdx.x;
    int bid = blockIdx.y * gridDim.x + blockIdx.x;
    const int nwg = gridDim.x * gridDim.y;
    if (!(nwg & 7)) bid = (bid & 7) * (nwg >> 3) + (bid >> 3);   // XCD swizzle
    const int n0 = (bid % gridDim.x) * 128;
    const int m0 = (bid / gridDim.x) * 128;
    const int lane = tid & 63;
    const int w = tid >> 6;             // 0..3
    const int wm = w >> 1, wn = w & 1;  // 2 (M) x 2 (N) waves
    const int lm = lane & 15, quad = lane >> 4;
    const int ck = ((quad * 16) ^ (((lm >> 1) & 3) << 4)) >> 1;  // ushort col

    const int srow = tid >> 2;                      // 0..63
    const int scolb = ((tid & 3) * 16) ^ (((tid >> 3) & 3) << 4);
    const char* gA = (const char*)A + ((size_t)(m0 + srow) * lda) * 2 + scolb;
    const char* gB = (const char*)Bt + ((size_t)(n0 + srow) * ldb) * 2 + scolb;
    const size_t strA = (size_t)64 * lda * 2;
    const size_t strB = (size_t)64 * ldb * 2;
    const int ldst = tid * 8;   // ushort offset of this thread's 16B chunk

    f32x4 acc[4][4];
    #pragma unroll
    for (int i = 0; i < 4; i++)
        #pragma unroll
        for (int j = 0; j < 4; j++) acc[i][j] = (f32x4){0.f, 0.f, 0.f, 0.f};

    const int NTt = K >> 5;

    auto STAGE = [&](int kt1, int buf) {
        const char* a = gA + (size_t)kt1 * 64;    // 32 bf16 = 64 B per K-tile
        const char* b = gB + (size_t)kt1 * 64;
        gl_lds16(a + 0 * strA, &LA[buf][0 * 2048 + ldst]);
        gl_lds16(a + 1 * strA, &LA[buf][1 * 2048 + ldst]);
        gl_lds16(b + 0 * strB, &LB[buf][0 * 2048 + ldst]);
        gl_lds16(b + 1 * strB, &LB[buf][1 * 2048 + ldst]);
    };

    // prologue: tiles 0,1 in flight (depth 2)
    STAGE(0, 0);
    STAGE(1, 1);

    int cur = 0;        // buffer holding tile kt
    int sb  = 2;        // buffer to stage tile kt+2 into
    for (int kt = 0; kt < NTt; ++kt) {
        __builtin_amdgcn_s_barrier();
        const int ahead = NTt - 1 - kt;
        if (ahead >= 2) {
            STAGE(kt + 2, sb);
            asm volatile("s_waitcnt vmcnt(8)" ::: "memory"); // kt landed; kt+1,kt+2 fly
        } else if (ahead == 1) {
            asm volatile("s_waitcnt vmcnt(4)" ::: "memory"); // kt landed; kt+1 flies
        } else {
            asm volatile("s_waitcnt vmcnt(0)" ::: "memory");
        }
        __builtin_amdgcn_s_barrier();   // collective: tile kt fully in LDS

        bf16x8 af[4], bf[4];
        #pragma unroll
        for (int s = 0; s < 4; s++)
            af[s] = *(const bf16x8*)&LA[cur][((wm * 64 + s * 16 + lm) << 5) + ck];
        #pragma unroll
        for (int t = 0; t < 4; t++)
            bf[t] = *(const bf16x8*)&LB[cur][((wn * 64 + t * 16 + lm) << 5) + ck];
        __builtin_amdgcn_s_setprio(1);
        #pragma unroll
        for (int s = 0; s < 4; s++)
            #pragma unroll
            for (int t = 0; t < 4; t++)
                acc[s][t] = __builtin_amdgcn_mfma_f32_16x16x32_bf16(
                    af[s], bf[t], acc[s][t], 0, 0, 0);
        __builtin_amdgcn_s_setprio(0);

        cur = (cur == 2) ? 0 : cur + 1;
        sb  = (sb == 2) ? 0 : sb + 1;
    }

    #pragma unroll
    for (int s = 0; s < 4; s++) {
        const int row = m0 + wm * 64 + s * 16 + quad * 4;
        #pragma unroll
        for (int t = 0; t < 4; t++) {
            const int col = n0 + wn * 64 + t * 16 + lm;
            #pragma unroll
            for (int r = 0; r < 4; r++)
                C[(size_t)(row + r) * ldc + col] = f2bf(acc[s][t][r]);
        }
    }
}

// ---------------------------------------------------------------------------
// 128x128 BK=64 bf16 MFMA GEMM (B^T form), r6's proven dbuf config. Used for
// GEMM2 (K=2048: fewer barriers than BK=32). OB: bf16 out, else fp32 with
// FUSED RMS row scale rsqrt(ss/DI+eps) (bitwise = old rms_finalize).
// ---------------------------------------------------------------------------
template <bool OB>
__global__ __launch_bounds__(256) void gemm128(
    const ushort_t* __restrict__ A, const ushort_t* __restrict__ Bt,
    void* __restrict__ Cp, const float* __restrict__ rowscale,
    int K, int lda, int ldb, int ldc)
{
    __shared__ __align__(16) ushort_t LA[2][128 * 64];
    __shared__ __align__(16) ushort_t LB[2][128 * 64];
    const int tid = threadIdx.x;
    int bid = blockIdx.y * gridDim.x + blockIdx.x;
    const int nwg = gridDim.x * gridDim.y;
    if (!(nwg & 7)) bid = (bid & 7) * (nwg >> 3) + (bid >> 3);   // XCD swizzle
    const int n0 = (bid % gridDim.x) * 128;
    const int m0 = (bid / gridDim.x) * 128;
    const int lane = tid & 63;
    const int w = tid >> 6;             // 0..3
    const int wm = w >> 1, wn = w & 1;  // 2 (M) x 2 (N) waves
    const int lm = lane & 15, quad = lane >> 4;
    const int swz = (lm & 7) << 4;                 // read-side XOR (bytes)
    const int ck0 = ((0 * 64 + quad * 16) ^ swz) >> 1;   // ushort col, kk=0
    const int ck1 = ((1 * 64 + quad * 16) ^ swz) >> 1;   // ushort col, kk=1

    const int srow = tid >> 3;                      // 0..31
    const int scolb = ((tid & 7) * 16) ^ ((srow & 7) << 4);
    const char* gA = (const char*)A + ((size_t)(m0 + srow) * lda) * 2 + scolb;
    const char* gB = (const char*)Bt + ((size_t)(n0 + srow) * ldb) * 2 + scolb;
    const size_t strA = (size_t)32 * lda * 2;
    const size_t strB = (size_t)32 * ldb * 2;
    const int ldst = tid * 8;   // ushort offset of this thread's 16B chunk

    f32x4 acc[4][4];
    #pragma unroll
    for (int i = 0; i < 4; i++)
        #pragma unroll
        for (int j = 0; j < 4; j++) acc[i][j] = (f32x4){0.f, 0.f, 0.f, 0.f};

    const int NTt = K >> 6;

    auto STAGE = [&](int kt1, int nxt) {
        const char* a = gA + (size_t)kt1 * 128;   // 64 bf16 = 128 B per K-tile
        const char* b = gB + (size_t)kt1 * 128;
        #pragma unroll
        for (int j = 0; j < 4; j++)
            gl_lds16(a + j * strA, &LA[nxt][j * 2048 + ldst]);
        #pragma unroll
        for (int j = 0; j < 4; j++)
            gl_lds16(b + j * strB, &LB[nxt][j * 2048 + ldst]);
    };

    STAGE(0, 0);   // prologue: 8 outstanding

    for (int kt = 0; kt < NTt; ++kt) {
        const int cur = kt & 1;
        __builtin_amdgcn_s_barrier();
        if (kt + 1 < NTt) {
            STAGE(kt + 1, cur ^ 1);
            asm volatile("s_waitcnt vmcnt(8)" ::: "memory");  // own kt loads done
        } else {
            asm volatile("s_waitcnt vmcnt(0)" ::: "memory");
        }
        __builtin_amdgcn_s_barrier();   // collective: tile kt fully in LDS

        bf16x8 af[4][2], bf[4][2];
        #pragma unroll
        for (int s = 0; s < 4; s++) {
            const int rb = (wm * 64 + s * 16 + lm) << 6;
            af[s][0] = *(const bf16x8*)&LA[cur][rb + ck0];
            af[s][1] = *(const bf16x8*)&LA[cur][rb + ck1];
        }
        #pragma unroll
        for (int t = 0; t < 4; t++) {
            const int rb = (wn * 64 + t * 16 + lm) << 6;
            bf[t][0] = *(const bf16x8*)&LB[cur][rb + ck0];
            bf[t][1] = *(const bf16x8*)&LB[cur][rb + ck1];
        }
        __builtin_amdgcn_s_setprio(1);
        #pragma unroll
        for (int kk = 0; kk < 2; kk++)
            #pragma unroll
            for (int s = 0; s < 4; s++)
                #pragma unroll
                for (int t = 0; t < 4; t++)
                    acc[s][t] = __builtin_amdgcn_mfma_f32_16x16x32_bf16(
                        af[s][kk], bf[t][kk], acc[s][t], 0, 0, 0);
        __builtin_amdgcn_s_setprio(0);
    }

    #pragma unroll
    for (int s = 0; s < 4; s++) {
        const int row = m0 + wm * 64 + s * 16 + quad * 4;
        float rs[4] = {1.f, 1.f, 1.f, 1.f};
        if (!OB && rowscale) {
            #pragma unroll
            for (int r = 0; r < 4; r++)
                rs[r] = rsqrtf(rowscale[row + r] * (1.f / DI) + 1e-5f);
        }
        #pragma unroll
        for (int t = 0; t < 4; t++) {
            const int col = n0 + wn * 64 + t * 16 + lm;
            #pragma unroll
            for (int r = 0; r < 4; r++) {
                if (OB)
                    ((ushort_t*)Cp)[(size_t)(row + r) * ldc + col] = f2bf(acc[s][t][r]);
                else
                    ((float*)Cp)[(size_t)(row + r) * ldc + col] = acc[s][t][r] * rs[r];
            }
        }
    }
}

// ---------------------------------------------------------------------------
// Depthwise causal conv (w=4) + bias + SiLU -> bf16 operand caches.
// ---------------------------------------------------------------------------
__global__ __launch_bounds__(256) void conv_silu_bf16(
    const ushort_t* __restrict__ xbcb, const float* __restrict__ cw,
    const float* __restrict__ cb, ushort_t* __restrict__ xT,
    ushort_t* __restrict__ Bn, ushort_t* __restrict__ BT,
    ushort_t* __restrict__ Cn)
{
    __shared__ ushort_t Tl[256][68];
    const int tid = threadIdx.x;
    const int c = blockIdx.x * 256 + tid;
    const int rb = blockIdx.y;
    const int row0 = rb * CONV_R;
    const bool isBC = (blockIdx.x == 8);

    const float w0 = cw[c*4+0], w1 = cw[c*4+1], w2 = cw[c*4+2], w3 = cw[c*4+3];
    const float bias = cb[c];
    float h0 = 0.f, h1 = 0.f, h2 = 0.f;
    if ((row0 & (LEN - 1)) != 0) {
        h0 = bf2f(xbcb[(size_t)(row0 - 3) * NPAD + c]);
        h1 = bf2f(xbcb[(size_t)(row0 - 2) * NPAD + c]);
        h2 = bf2f(xbcb[(size_t)(row0 - 1) * NPAD + c]);
    }
    const ushort_t* p = xbcb + (size_t)row0 * NPAD + c;
    for (int r = 0; r < CONV_R; r++) {
        float xin = bf2f(*p);
        float a = bias + w0*h0 + w1*h1 + w2*h2 + w3*xin;
        ushort_t bv = f2bf(a / (1.f + __expf(-a)));
        Tl[tid][r] = bv;
        if (isBC) {
            int row = row0 + r;
            if (tid < DS) Bn[(size_t)row * DS + tid] = bv;
            else          Cn[(size_t)row * DS + (tid - DS)] = bv;
        }
        h0 = h1; h1 = h2; h2 = xin;
        p += NPAD;
    }
    __syncthreads();

    const int seg = tid & 7;
    const int clb = tid >> 3;
    if (!isBC) {
        #pragma unroll
        for (int pass = 0; pass < 8; pass++) {
            int cl = pass * 32 + clb;
            int cc = blockIdx.x * 256 + cl;
            us8 v;
            #pragma unroll
            for (int j = 0; j < 8; j++) v[j] = Tl[cl][seg * 8 + j];
            *(us8*)&xT[(size_t)cc * NTOK + row0 + seg * 8] = v;
        }
    } else {
        #pragma unroll
        for (int pass = 0; pass < 4; pass++) {
            int n = pass * 32 + clb;
            us8 v;
            #pragma unroll
            for (int j = 0; j < 8; j++) v[j] = Tl[n][seg * 8 + j];
            *(us8*)&BT[(size_t)n * NTOK + row0 + seg * 8] = v;
        }
    }
}

// ---------------------------------------------------------------------------
// Batched head-independent GEMM: Graw[bc][t][s] = sum_n C[t,n]*B[s,n].
// ---------------------------------------------------------------------------
__global__ __launch_bounds__(256) void gct_gemm(
    const ushort_t* __restrict__ Bn, const ushort_t* __restrict__ Cn,
    float* __restrict__ Graw)
{
    const int bc = blockIdx.x;             // b*NCH + chunk
    const int chunk = bc % NCH;
    const int b = bc / NCH;
    const size_t rowbase = (size_t)b * LEN + (size_t)chunk * QCH;
    const int tid = threadIdx.x;
    const int w = tid >> 6, lane = tid & 63;
    const int lm = lane & 15, quad = lane >> 4;
    const int tw0 = w * 32;

    f32x4 acc[2][8];
    #pragma unroll
    for (int ti = 0; ti < 2; ti++)
        #pragma unroll
        for (int sj = 0; sj < 8; sj++) acc[ti][sj] = (f32x4){0.f, 0.f, 0.f, 0.f};

    #pragma unroll
    for (int ks = 0; ks < 4; ks++) {
        const int k0 = ks * 32 + quad * 8;
        bf16x8 a0 = *(const bf16x8*)&Cn[(rowbase + tw0 + lm) * DS + k0];
        bf16x8 a1 = *(const bf16x8*)&Cn[(rowbase + tw0 + 16 + lm) * DS + k0];
        #pragma unroll
        for (int sj = 0; sj < 8; sj++) {
            bf16x8 bb = *(const bf16x8*)&Bn[(rowbase + sj * 16 + lm) * DS + k0];
            acc[0][sj] = __builtin_amdgcn_mfma_f32_16x16x32_bf16(a0, bb, acc[0][sj], 0, 0, 0);
            acc[1][sj] = __builtin_amdgcn_mfma_f32_16x16x32_bf16(a1, bb, acc[1][sj], 0, 0, 0);
        }
    }
    float* G = Graw + (size_t)bc * (QCH * QCH);
    #pragma unroll
    for (int ti = 0; ti < 2; ti++)
        #pragma unroll
        for (int sj = 0; sj < 8; sj++)
            #pragma unroll
            for (int r = 0; r < 4; r++)
                G[(size_t)(tw0 + ti * 16 + quad * 4 + r) * QCH + sj * 16 + lm] = acc[ti][sj][r];
}

// ---------------------------------------------------------------------------
// dt in FULL fp32 straight from hidden @ W_in[:, TOFF:] (exp-amplified path).
// ---------------------------------------------------------------------------
__global__ __launch_bounds__(256) void dt_proc_fp32(
    const float* __restrict__ hidden, const float* __restrict__ W_in,
    const float* __restrict__ dt_bias, const float* __restrict__ A_log,
    float* __restrict__ dtv, float* __restrict__ ldA)
{
    const int h = threadIdx.x & 31;
    const int tt = threadIdx.x >> 5;
    const int t = blockIdx.x * 8 + tt;
    const float* hr = hidden + (size_t)t * DM;
    const float* wc = W_in + TOFF + h;
    float a0 = 0.f, a1 = 0.f, a2 = 0.f, a3 = 0.f;
    for (int k = 0; k < DM; k += 4) {
        a0 += hr[k+0] * wc[(size_t)(k+0) * DP];
        a1 += hr[k+1] * wc[(size_t)(k+1) * DP];
        a2 += hr[k+2] * wc[(size_t)(k+2) * DP];
        a3 += hr[k+3] * wc[(size_t)(k+3) * DP];
    }
    float v = (a0 + a1) + (a2 + a3) + dt_bias[h];
    float sp = (v > 20.f) ? v : log1pf(expf(v));
    int idx = t * NH + h;
    dtv[idx] = sp;
    ldA[idx] = -sp * expf(A_log[h]);
}

// ---------------------------------------------------------------------------
// Per-(b,h,chunk) prefix scan of ldA (one wave per block, shfl-based).
// ---------------------------------------------------------------------------
__global__ __launch_bounds__(64) void scan_chunk(
    const float* __restrict__ dtv, const float* __restrict__ ldA,
    float* __restrict__ lcpb, float* __restrict__ dtsb,
    float* __restrict__ coefb, float* __restrict__ csum)
{
    const int blk = blockIdx.x;            // bh*NCH + chunk
    const int chunk = blk % NCH;
    const int bh = blk / NCH;
    const int h = bh % NH;
    const int b = bh / NH;
    const int lane = threadIdx.x;
    const size_t rowbase = (size_t)b * LEN + (size_t)chunk * QCH;
    const int t0 = 2 * lane, t1 = 2 * lane + 1;
    float v0 = ldA[(rowbase + t0) * NH + h];
    float v1 = ldA[(rowbase + t1) * NH + h];
    float d0 = dtv[(rowbase + t0) * NH + h];
    float d1 = dtv[(rowbase + t1) * NH + h];
    float pair = v0 + v1;
    #pragma unroll
    for (int off = 1; off < 64; off <<= 1) {
        float n = __shfl_up(pair, off, 64);
        if (lane >= off) pair += n;
    }
    float l1 = pair, l0 = pair - v1;
    float total = __shfl(pair, 63, 64);
    size_t base = (size_t)blk * QCH;
    *(float2*)&lcpb[base + t0] = make_float2(l0, l1);
    *(float2*)&dtsb[base + t0] = make_float2(d0, d1);
    *(float2*)&coefb[base + t0] =
        make_float2(__expf(total - l0) * d0, __expf(total - l1) * d1);
    if (lane == 63) csum[blk] = total;
}

// ---------------------------------------------------------------------------
// FUSED Phase 1+2 (r9-measured config: 256 blocks, nhalf split; all 4 waves
// of a block share the same 64 xT rows via L1 -> no read replication).
// Per (b,h,nhalf) block, loop chunks c=0..15:
//   acc(c)[p][n] = sum_s (coef_s*x[s,p])*B[s,n]  (MFMA, same k-order)
//   hsb[c] = f2bf(run); run = exp(csum[c])*run + acc  (identical numerics)
// ---------------------------------------------------------------------------
__global__ __launch_bounds__(256) void phase12_fused(
    const ushort_t* __restrict__ xT, const ushort_t* __restrict__ BT,
    const float* __restrict__ coefb, const float* __restrict__ csum,
    ushort_t* __restrict__ hsb)
{
    const int blk = blockIdx.x;            // (b*NH + h)*2 + nhalf
    const int nhalf = blk & 1;
    const int bh = blk >> 1;
    const int h = bh & (NH - 1);
    const int b = bh >> 5;
    const int tid = threadIdx.x;
    const int w = tid >> 6, lane = tid & 63;
    const int lm = lane & 15, quad = lane >> 4;
    const int nw0 = nhalf * 64 + w * 16;   // 16 n-cols per wave

    f32x4 run[4];
    #pragma unroll
    for (int mi = 0; mi < 4; mi++) run[mi] = (f32x4){0.f, 0.f, 0.f, 0.f};

    for (int c = 0; c < NCH; c++) {
        const size_t rowbase = (size_t)b * LEN + (size_t)c * QCH;
        const size_t cb = ((size_t)bh * NCH + c) * QCH;
        const float P = __expf(csum[bh * NCH + c]);

        f32x4 acc[4];
        #pragma unroll
        for (int mi = 0; mi < 4; mi++) acc[mi] = (f32x4){0.f, 0.f, 0.f, 0.f};

        #pragma unroll
        for (int ks = 0; ks < 4; ks++) {
            const int k0 = ks * 32 + quad * 8;
            bf16x8 a[4];
            #pragma unroll
            for (int mi = 0; mi < 4; mi++)
                a[mi] = *(const bf16x8*)&xT[(size_t)(h * HD + mi * 16 + lm) * NTOK + rowbase + k0];
            float4 c0 = *(const float4*)&coefb[cb + k0];
            float4 c1 = *(const float4*)&coefb[cb + k0 + 4];
            float cf[8] = { c0.x, c0.y, c0.z, c0.w, c1.x, c1.y, c1.z, c1.w };
            us8 raw = *(const us8*)&BT[(size_t)(nw0 + lm) * NTOK + rowbase + k0];
            us8 sb;
            #pragma unroll
            for (int j = 0; j < 8; j++) sb[j] = f2bf(bf2f(raw[j]) * cf[j]);
            bf16x8 bfr = us2bf(sb);
            __builtin_amdgcn_s_setprio(1);
            #pragma unroll
            for (int mi = 0; mi < 4; mi++)
                acc[mi] = __builtin_amdgcn_mfma_f32_16x16x32_bf16(a[mi], bfr, acc[mi], 0, 0, 0);
            __builtin_amdgcn_s_setprio(0);
        }

        // write h_start (pre-update run), then recurrence update
        ushort_t* hb = hsb + ((size_t)bh * NCH + c) * (HD * DS);
        #pragma unroll
        for (int mi = 0; mi < 4; mi++)
            #pragma unroll
            for (int r = 0; r < 4; r++)
                hb[(size_t)(mi * 16 + quad * 4 + r) * DS + nw0 + lm] = f2bf(run[mi][r]);
        #pragma unroll
        for (int mi = 0; mi < 4; mi++)
            #pragma unroll
            for (int r = 0; r < 4; r++)
                run[mi][r] = P * run[mi][r] + acc[mi][r];
    }
}

// ---------------------------------------------------------------------------
// Phase 3 (MFMA) + FUSED GATE: Y = G@X + Chat@hs^T; epilogue adds D*x,
// multiplies silu(z) (gate), writes gated bf16 v into zxb's dead xBC slice
// (cols DI.., ld=NPAD) and accumulates per-token sum(v^2) via atomics.
// ---------------------------------------------------------------------------
__global__ __launch_bounds__(256) void phase3_mfma(
    const ushort_t* __restrict__ xT, const ushort_t* __restrict__ Cn,
    const ushort_t* __restrict__ hsb, const float* __restrict__ Graw,
    const float* __restrict__ lcpb, const float* __restrict__ dtsb,
    const float* __restrict__ Dvec, ushort_t* __restrict__ zxb,
    float* __restrict__ ss)
{
    const int tid = threadIdx.x;
    const int h = blockIdx.x & (NH - 1);
    const int bc = blockIdx.x >> 5;        // b*NCH + chunk
    const int chunk = bc % NCH;
    const int b = bc / NCH;
    const int blko = (b * NH + h) * NCH + chunk;
    const size_t rowbase = (size_t)b * LEN + (size_t)chunk * QCH;

    __shared__ float lcp[QCH];
    __shared__ float dts[QCH];
    if (tid < QCH) {
        lcp[tid] = lcpb[(size_t)blko * QCH + tid];
        dts[tid] = dtsb[(size_t)blko * QCH + tid];
    }
    __syncthreads();

    const int w = tid >> 6, lane = tid & 63;
    const int lm = lane & 15, quad = lane >> 4;
    const int tw0 = w * 32;

    const float* Gr = Graw + (size_t)bc * (QCH * QCH);
    const ushort_t* hsp = hsb + (size_t)blko * (HD * DS);

    f32x4 acc2[2][4];
    #pragma unroll
    for (int ti = 0; ti < 2; ti++)
        #pragma unroll
        for (int pi = 0; pi < 4; pi++) acc2[ti][pi] = (f32x4){0.f, 0.f, 0.f, 0.f};

    #pragma unroll
    for (int ks = 0; ks < 8; ks++) {
        bf16x8 a[2], bb[4];
        if (ks < 4) {
            const int k0 = ks * 32 + quad * 8;
            #pragma unroll
            for (int ti = 0; ti < 2; ti++) {
                int t = tw0 + ti * 16 + lm;
                float lt = lcp[t];
                const float* gp = Gr + (size_t)t * QCH + k0;
                float4 g0 = *(const float4*)gp;
                float4 g1 = *(const float4*)(gp + 4);
                float ge[8] = { g0.x, g0.y, g0.z, g0.w, g1.x, g1.y, g1.z, g1.w };
                us8 sb;
                #pragma unroll
                for (int j = 0; j < 8; j++) {
                    int s = k0 + j;
                    float wv = (s <= t) ? (__expf(lt - lcp[s]) * dts[s]) : 0.f;
                    sb[j] = f2bf(ge[j] * wv);
                }
                a[ti] = us2bf(sb);
            }
            #pragma unroll
            for (int pi = 0; pi < 4; pi++)
                bb[pi] = *(const bf16x8*)&xT[(size_t)(h * HD + pi * 16 + lm) * NTOK + rowbase + k0];
        } else {
            const int k0 = (ks - 4) * 32 + quad * 8;
            #pragma unroll
            for (int ti = 0; ti < 2; ti++) {
                int t = tw0 + ti * 16 + lm;
                float sc = __expf(lcp[t]);
                us8 raw = *(const us8*)&Cn[(rowbase + t) * DS + k0];
                us8 sb;
                #pragma unroll
                for (int j = 0; j < 8; j++) sb[j] = f2bf(bf2f(raw[j]) * sc);
                a[ti] = us2bf(sb);
            }
            #pragma unroll
            for (int pi = 0; pi < 4; pi++)
                bb[pi] = *(const bf16x8*)&hsp[(size_t)(pi * 16 + lm) * DS + k0];
        }
        __builtin_amdgcn_s_setprio(1);
        #pragma unroll
        for (int ti = 0; ti < 2; ti++)
            #pragma unroll
            for (int pi = 0; pi < 4; pi++)
                acc2[ti][pi] = __builtin_amdgcn_mfma_f32_16x16x32_bf16(a[ti], bb[pi], acc2[ti][pi], 0, 0, 0);
        __builtin_amdgcn_s_setprio(0);
    }

    const float Dh = Dvec[h];
    float vsq[2][4] = {};
    #pragma unroll
    for (int ti = 0; ti < 2; ti++)
        #pragma unroll
        for (int pi = 0; pi < 4; pi++) {
            int tb = tw0 + ti * 16 + quad * 4;
            int col = h * HD + pi * 16 + lm;
            ushort4 xv = *(const ushort4*)&xT[(size_t)(h * HD + pi * 16 + lm) * NTOK + rowbase + tb];
            const ushort_t* xe = (const ushort_t*)&xv;
            #pragma unroll
            for (int r = 0; r < 4; r++) {
                size_t grow = rowbase + tb + r;
                float y = acc2[ti][pi][r] + Dh * bf2f(xe[r]);
                float z = bf2f(zxb[grow * NPAD + col]);
                float v = y * (z / (1.f + __expf(-z)));
                vsq[ti][r] += v * v;
                zxb[grow * NPAD + DI + col] = f2bf(v);
            }
        }
    #pragma unroll
    for (int ti = 0; ti < 2; ti++)
        #pragma unroll
        for (int r = 0; r < 4; r++) {
            float s = vsq[ti][r];
            s += __shfl_xor(s, 1, 64);
            s += __shfl_xor(s, 2, 64);
            s += __shfl_xor(s, 4, 64);
            s += __shfl_xor(s, 8, 64);
            if (lm == 0) {
                int tb = tw0 + ti * 16 + quad * 4 + r;
                atomicAdd(&ss[rowbase + tb], s);
            }
        }
}

// ---------------------------------------------------------------------------
extern "C" void kernel_launch(void* const* d_in, const int* in_sizes, int n_in,
                              void* d_out, int out_size, void* d_ws, size_t ws_size,
                              hipStream_t stream)
{
    const float* hidden  = (const float*)d_in[0];
    const float* W_in    = (const float*)d_in[1];
    const float* conv_w  = (const float*)d_in[2];
    const float* conv_b  = (const float*)d_in[3];
    const float* dt_bias = (const float*)d_in[4];
    const float* A_log   = (const float*)d_in[5];
    const float* Dv      = (const float*)d_in[6];
    const float* norm_w  = (const float*)d_in[7];
    const float* W_out   = (const float*)d_in[8];
    float* out = (float*)d_out;

    char* ws = (char*)d_ws;
    size_t o = 0;
    ushort_t* zxb  = (ushort_t*)(ws + o); o += (size_t)NTOK * NPAD * 2;             // 71.3 MB
    float* S       = (float*)(ws + o);    o += (size_t)BSZ * NH * NCH * HD * DS * 4;// 67.1 MB (Ah/W1t alias region)
    ushort_t* xT   = (ushort_t*)(ws + o); o += (size_t)DI * NTOK * 2;               // 33.6 MB
    ushort_t* Bn   = (ushort_t*)(ws + o); o += (size_t)NTOK * DS * 2;               // 2.1 MB
    ushort_t* BT   = (ushort_t*)(ws + o); o += (size_t)DS * NTOK * 2;               // 2.1 MB
    ushort_t* Cn   = (ushort_t*)(ws + o); o += (size_t)NTOK * DS * 2;               // 2.1 MB
    ushort_t* hsb  = (ushort_t*)(ws + o); o += (size_t)BSZ * NH * NCH * HD * DS * 2;// 33.6 MB
    float* Graw    = (float*)(ws + o);    o += (size_t)BSZ * NCH * QCH * QCH * 4;   // 4.2 MB
    float* dtv     = (float*)(ws + o);    o += (size_t)NTOK * NH * 4;
    float* ldA     = (float*)(ws + o);    o += (size_t)NTOK * NH * 4;
    float* lcpb    = (float*)(ws + o);    o += (size_t)BSZ * NH * LEN * 4;
    float* dtsb    = (float*)(ws + o);    o += (size_t)BSZ * NH * LEN * 4;
    float* coefb   = (float*)(ws + o);    o += (size_t)BSZ * NH * LEN * 4;
    float* csum    = (float*)(ws + o);    o += (size_t)BSZ * NH * NCH * 4;
    float* ss      = (float*)(ws + o);    o += (size_t)NTOK * 4;
    (void)S;
    // Aliases (dead-region reuse):
    ushort_t* Ah   = (ushort_t*)S;                                   // GEMM1 A (bf16 hidden)
    ushort_t* W1t  = (ushort_t*)((char*)S + (size_t)NTOK * DM * 2);  // GEMM1 B^T
    ushort_t* Wot  = hsb;                                            // post-phase3 (hsb dead)
    ushort_t* xbcb = zxb + DI;                                       // xBC slice, ld=NPAD
    ushort_t* ynb  = zxb + DI;                                       // gated-v slice (post-conv), ld=NPAD

    // 0) zero the sum-of-squares accumulator (consumed by phase3 atomics)
    hipMemsetAsync(ss, 0, (size_t)NTOK * 4, stream);
    // 1) bf16 conversions for GEMM1
    cvt_bf16<<<(NTOK * DM) / 1024, 256, 0, stream>>>(hidden, Ah);
    transpose_cvt<<<dim3(NPAD / 32, DM / 32), 256, 0, stream>>>(
        W_in, W1t, nullptr, DM, NPAD, DP);
    // 2) GEMM1 (merged z + xBC, bf16 out) — r8 kernel, split into two M-half
    //    dispatches (~51 us each) so sub-51us kernels surface in the top-5.
    gemm1_tb<<<dim3(NPAD / 128, NTOK / 256), 256, 0, stream>>>(
        Ah, W1t, zxb, DM, DM, DM, NPAD);
    gemm1_tb<<<dim3(NPAD / 128, NTOK / 256), 256, 0, stream>>>(
        Ah + (size_t)(NTOK / 2) * DM, W1t,
        zxb + (size_t)(NTOK / 2) * NPAD, DM, DM, DM, NPAD);
    // 3) conv + SiLU -> bf16 operand caches
    conv_silu_bf16<<<dim3(CD / 256, NRB), 256, 0, stream>>>(
        xbcb, conv_w, conv_b, xT, Bn, BT, Cn);
    // 4) head-shared C.B^T (once per (b,chunk))
    gct_gemm<<<BSZ * NCH, 256, 0, stream>>>(Bn, Cn, Graw);
    // 5) dt in fp32 + hoisted per-chunk prefix scan
    dt_proc_fp32<<<NTOK / 8, 256, 0, stream>>>(hidden, W_in, dt_bias, A_log, dtv, ldA);
    scan_chunk<<<BSZ * NH * NCH, 64, 0, stream>>>(dtv, ldA, lcpb, dtsb, coefb, csum);
    // 6+7) FUSED chunk states + cross-chunk recurrence -> bf16 h_start.
    //      256 blocks (r9-measured config; 1024-block n-split regressed r10:
    //      xT read replication 67->268 MB through L2/L3).
    phase12_fused<<<BSZ * NH * 2, 256, 0, stream>>>(xT, BT, coefb, csum, hsb);
    // 8) per-chunk outputs + fused gate -> gated bf16 v into zxb xBC slice,
    //    per-token sum(v^2) via atomics
    phase3_mfma<<<BSZ * NH * NCH, 256, 0, stream>>>(
        xT, Cn, hsb, Graw, lcpb, dtsb, Dv, zxb, ss);
    // 9) W_out transpose (hsb dead) with norm_w folded in, then
    //    out = (v @ diag(nw) W_out) * rsqrt(ss/DI+eps)  (RMS fused in epilogue)
    transpose_cvt<<<dim3(DM / 32, DI / 32), 256, 0, stream>>>(
        W_out, Wot, norm_w, DI, DM, DM);
    gemm128<false><<<dim3(DM / 128, NTOK / 128), 256, 0, stream>>>(
        ynb, Wot, out, ss, DI, NPAD, DI, DM);
}

// Round 15
// 482.112 us; speedup vs baseline: 1.1201x; 1.0720x over previous
//
#include <hip/hip_runtime.h>
#include <math.h>

#define BSZ 4
#define LEN 2048
#define DM 1024
#define DI 2048
#define HD 64      // HEADDIM (p)
#define NH 32      // NHEADS
#define DS 128     // D_STATE (n)
#define CD 2304    // CONV_DIM
#define DP 4384    // D_IN_PROJ
#define NTOK (BSZ*LEN)   // 8192
#define QCH 128          // chunk length
#define NCH (LEN/QCH)    // 16 chunks
#define TOFF (DP-NH)     // 4352: dt raw cols in W_in

#define CONV_R 64
#define NRB (NTOK/CONV_R)
#define NPAD 4352        // z + xBC exactly (dt handled in fp32 path)

typedef unsigned short ushort_t;
typedef __bf16 bf16x8 __attribute__((ext_vector_type(8)));
typedef ushort_t us8 __attribute__((ext_vector_type(8)));
typedef float f32x4 __attribute__((ext_vector_type(4)));

__device__ __forceinline__ ushort_t f2bf(float f) {
    unsigned u = __float_as_uint(f);
    unsigned r = (u + 0x7FFFu + ((u >> 16) & 1u)) >> 16;
    return (ushort_t)r;
}
__device__ __forceinline__ float bf2f(ushort_t u) {
    return __uint_as_float(((unsigned)u) << 16);
}
__device__ __forceinline__ bf16x8 us2bf(us8 v) {
    union { us8 u; bf16x8 b; } x; x.u = v; return x.b;
}

__device__ __forceinline__ void gl_lds16(const void* g, void* l) {
    __builtin_amdgcn_global_load_lds(
        (const __attribute__((address_space(1))) void*)g,
        (__attribute__((address_space(3))) void*)l, 16, 0, 0);
}

// ---------------------------------------------------------------------------
// fp32 -> bf16 elementwise (hidden). 4 elems/thread.
// ---------------------------------------------------------------------------
__global__ __launch_bounds__(256) void cvt_bf16(
    const float* __restrict__ A, ushort_t* __restrict__ Ab)
{
    size_t i = ((size_t)blockIdx.x * 256 + threadIdx.x) * 4;
    float4 v = *(const float4*)(A + i);
    ushort_t o[4] = { f2bf(v.x), f2bf(v.y), f2bf(v.z), f2bf(v.w) };
    *(uint2*)(Ab + i) = *(uint2*)o;
}

// ---------------------------------------------------------------------------
// W[k][n] fp32 (ld=ldw) -> Wt[n][k] bf16 (ld=K), zero-pad for n >= N.
// Optional per-k column scale (used to fold norm_w into W_out).
// ---------------------------------------------------------------------------
__global__ __launch_bounds__(256) void transpose_cvt(
    const float* __restrict__ W, ushort_t* __restrict__ Wt,
    const float* __restrict__ colscale, int K, int N, int ldw)
{
    __shared__ float T[32][33];
    const int n0 = blockIdx.x * 32;
    const int k0 = blockIdx.y * 32;
    const int tid = threadIdx.x;
    #pragma unroll
    for (int l = 0; l < 4; l++) {
        int idx = tid + l * 256;
        int ki = idx >> 5, nj = idx & 31;
        int n = n0 + nj;
        float s = colscale ? colscale[k0 + ki] : 1.f;
        T[ki][nj] = (n < N) ? W[(size_t)(k0 + ki) * ldw + n] * s : 0.f;
    }
    __syncthreads();
    #pragma unroll
    for (int l = 0; l < 4; l++) {
        int idx = tid + l * 256;
        int nj = idx >> 5, ki = idx & 31;
        Wt[(size_t)(n0 + nj) * K + k0 + ki] = f2bf(T[ki][nj]);
    }
}

// ---------------------------------------------------------------------------
// GEMM1: 128x128 BK=32, TRIPLE-buffered (48 KiB -> 3 blocks/CU). Depth-2
// prefetch with counted vmcnt ladder 8/4/0; swizzle byte^=((row>>1)&3)<<4
// (0 conflicts). Parked local optimum (~101 us full-M, r8). Launched as TWO
// M-half dispatches (diagnostic: lets sub-51us kernels surface in top-5).
// ---------------------------------------------------------------------------
__global__ __launch_bounds__(256, 3) void gemm1_tb(
    const ushort_t* __restrict__ A, const ushort_t* __restrict__ Bt,
    ushort_t* __restrict__ C, int K, int lda, int ldb, int ldc)
{
    __shared__ __align__(16) ushort_t LA[3][128 * 32];
    __shared__ __align__(16) ushort_t LB[3][128 * 32];
    const int tid = threadIdx.x;
    int bid = blockIdx.y * gridDim.x + blockIdx.x;
    const int nwg = gridDim.x * gridDim.y;
    if (!(nwg & 7)) bid = (bid & 7) * (nwg >> 3) + (bid >> 3);   // XCD swizzle
    const int n0 = (bid % gridDim.x) * 128;
    const int m0 = (bid / gridDim.x) * 128;
    const int lane = tid & 63;
    const int w = tid >> 6;             // 0..3
    const int wm = w >> 1, wn = w & 1;  // 2 (M) x 2 (N) waves
    const int lm = lane & 15, quad = lane >> 4;
    const int ck = ((quad * 16) ^ (((lm >> 1) & 3) << 4)) >> 1;  // ushort col

    const int srow = tid >> 2;                      // 0..63
    const int scolb = ((tid & 3) * 16) ^ (((tid >> 3) & 3) << 4);
    const char* gA = (const char*)A + ((size_t)(m0 + srow) * lda) * 2 + scolb;
    const char* gB = (const char*)Bt + ((size_t)(n0 + srow) * ldb) * 2 + scolb;
    const size_t strA = (size_t)64 * lda * 2;
    const size_t strB = (size_t)64 * ldb * 2;
    const int ldst = tid * 8;   // ushort offset of this thread's 16B chunk

    f32x4 acc[4][4];
    #pragma unroll
    for (int i = 0; i < 4; i++)
        #pragma unroll
        for (int j = 0; j < 4; j++) acc[i][j] = (f32x4){0.f, 0.f, 0.f, 0.f};

    const int NTt = K >> 5;

    auto STAGE = [&](int kt1, int buf) {
        const char* a = gA + (size_t)kt1 * 64;    // 32 bf16 = 64 B per K-tile
        const char* b = gB + (size_t)kt1 * 64;
        gl_lds16(a + 0 * strA, &LA[buf][0 * 2048 + ldst]);
        gl_lds16(a + 1 * strA, &LA[buf][1 * 2048 + ldst]);
        gl_lds16(b + 0 * strB, &LB[buf][0 * 2048 + ldst]);
        gl_lds16(b + 1 * strB, &LB[buf][1 * 2048 + ldst]);
    };

    // prologue: tiles 0,1 in flight (depth 2)
    STAGE(0, 0);
    STAGE(1, 1);

    int cur = 0;        // buffer holding tile kt
    int sb  = 2;        // buffer to stage tile kt+2 into
    for (int kt = 0; kt < NTt; ++kt) {
        __builtin_amdgcn_s_barrier();
        const int ahead = NTt - 1 - kt;
        if (ahead >= 2) {
            STAGE(kt + 2, sb);
            asm volatile("s_waitcnt vmcnt(8)" ::: "memory"); // kt landed; kt+1,kt+2 fly
        } else if (ahead == 1) {
            asm volatile("s_waitcnt vmcnt(4)" ::: "memory"); // kt landed; kt+1 flies
        } else {
            asm volatile("s_waitcnt vmcnt(0)" ::: "memory");
        }
        __builtin_amdgcn_s_barrier();   // collective: tile kt fully in LDS

        bf16x8 af[4], bf[4];
        #pragma unroll
        for (int s = 0; s < 4; s++)
            af[s] = *(const bf16x8*)&LA[cur][((wm * 64 + s * 16 + lm) << 5) + ck];
        #pragma unroll
        for (int t = 0; t < 4; t++)
            bf[t] = *(const bf16x8*)&LB[cur][((wn * 64 + t * 16 + lm) << 5) + ck];
        __builtin_amdgcn_s_setprio(1);
        #pragma unroll
        for (int s = 0; s < 4; s++)
            #pragma unroll
            for (int t = 0; t < 4; t++)
                acc[s][t] = __builtin_amdgcn_mfma_f32_16x16x32_bf16(
                    af[s], bf[t], acc[s][t], 0, 0, 0);
        __builtin_amdgcn_s_setprio(0);

        cur = (cur == 2) ? 0 : cur + 1;
        sb  = (sb == 2) ? 0 : sb + 1;
    }

    #pragma unroll
    for (int s = 0; s < 4; s++) {
        const int row = m0 + wm * 64 + s * 16 + quad * 4;
        #pragma unroll
        for (int t = 0; t < 4; t++) {
            const int col = n0 + wn * 64 + t * 16 + lm;
            #pragma unroll
            for (int r = 0; r < 4; r++)
                C[(size_t)(row + r) * ldc + col] = f2bf(acc[s][t][r]);
        }
    }
}

// ---------------------------------------------------------------------------
// 128x128 BK=64 bf16 MFMA GEMM (B^T form), r6's proven dbuf config. Used for
// GEMM2 (K=2048: fewer barriers than BK=32). OB: bf16 out, else fp32 with
// FUSED RMS row scale rsqrt(ss/DI+eps) (bitwise = old rms_finalize).
// ---------------------------------------------------------------------------
template <bool OB>
__global__ __launch_bounds__(256) void gemm128(
    const ushort_t* __restrict__ A, const ushort_t* __restrict__ Bt,
    void* __restrict__ Cp, const float* __restrict__ rowscale,
    int K, int lda, int ldb, int ldc)
{
    __shared__ __align__(16) ushort_t LA[2][128 * 64];
    __shared__ __align__(16) ushort_t LB[2][128 * 64];
    const int tid = threadIdx.x;
    int bid = blockIdx.y * gridDim.x + blockIdx.x;
    const int nwg = gridDim.x * gridDim.y;
    if (!(nwg & 7)) bid = (bid & 7) * (nwg >> 3) + (bid >> 3);   // XCD swizzle
    const int n0 = (bid % gridDim.x) * 128;
    const int m0 = (bid / gridDim.x) * 128;
    const int lane = tid & 63;
    const int w = tid >> 6;             // 0..3
    const int wm = w >> 1, wn = w & 1;  // 2 (M) x 2 (N) waves
    const int lm = lane & 15, quad = lane >> 4;
    const int swz = (lm & 7) << 4;                 // read-side XOR (bytes)
    const int ck0 = ((0 * 64 + quad * 16) ^ swz) >> 1;   // ushort col, kk=0
    const int ck1 = ((1 * 64 + quad * 16) ^ swz) >> 1;   // ushort col, kk=1

    const int srow = tid >> 3;                      // 0..31
    const int scolb = ((tid & 7) * 16) ^ ((srow & 7) << 4);
    const char* gA = (const char*)A + ((size_t)(m0 + srow) * lda) * 2 + scolb;
    const char* gB = (const char*)Bt + ((size_t)(n0 + srow) * ldb) * 2 + scolb;
    const size_t strA = (size_t)32 * lda * 2;
    const size_t strB = (size_t)32 * ldb * 2;
    const int ldst = tid * 8;   // ushort offset of this thread's 16B chunk

    f32x4 acc[4][4];
    #pragma unroll
    for (int i = 0; i < 4; i++)
        #pragma unroll
        for (int j = 0; j < 4; j++) acc[i][j] = (f32x4){0.f, 0.f, 0.f, 0.f};

    const int NTt = K >> 6;

    auto STAGE = [&](int kt1, int nxt) {
        const char* a = gA + (size_t)kt1 * 128;   // 64 bf16 = 128 B per K-tile
        const char* b = gB + (size_t)kt1 * 128;
        #pragma unroll
        for (int j = 0; j < 4; j++)
            gl_lds16(a + j * strA, &LA[nxt][j * 2048 + ldst]);
        #pragma unroll
        for (int j = 0; j < 4; j++)
            gl_lds16(b + j * strB, &LB[nxt][j * 2048 + ldst]);
    };

    STAGE(0, 0);   // prologue: 8 outstanding

    for (int kt = 0; kt < NTt; ++kt) {
        const int cur = kt & 1;
        __builtin_amdgcn_s_barrier();
        if (kt + 1 < NTt) {
            STAGE(kt + 1, cur ^ 1);
            asm volatile("s_waitcnt vmcnt(8)" ::: "memory");  // own kt loads done
        } else {
            asm volatile("s_waitcnt vmcnt(0)" ::: "memory");
        }
        __builtin_amdgcn_s_barrier();   // collective: tile kt fully in LDS

        bf16x8 af[4][2], bf[4][2];
        #pragma unroll
        for (int s = 0; s < 4; s++) {
            const int rb = (wm * 64 + s * 16 + lm) << 6;
            af[s][0] = *(const bf16x8*)&LA[cur][rb + ck0];
            af[s][1] = *(const bf16x8*)&LA[cur][rb + ck1];
        }
        #pragma unroll
        for (int t = 0; t < 4; t++) {
            const int rb = (wn * 64 + t * 16 + lm) << 6;
            bf[t][0] = *(const bf16x8*)&LB[cur][rb + ck0];
            bf[t][1] = *(const bf16x8*)&LB[cur][rb + ck1];
        }
        __builtin_amdgcn_s_setprio(1);
        #pragma unroll
        for (int kk = 0; kk < 2; kk++)
            #pragma unroll
            for (int s = 0; s < 4; s++)
                #pragma unroll
                for (int t = 0; t < 4; t++)
                    acc[s][t] = __builtin_amdgcn_mfma_f32_16x16x32_bf16(
                        af[s][kk], bf[t][kk], acc[s][t], 0, 0, 0);
        __builtin_amdgcn_s_setprio(0);
    }

    #pragma unroll
    for (int s = 0; s < 4; s++) {
        const int row = m0 + wm * 64 + s * 16 + quad * 4;
        float rs[4] = {1.f, 1.f, 1.f, 1.f};
        if (!OB && rowscale) {
            #pragma unroll
            for (int r = 0; r < 4; r++)
                rs[r] = rsqrtf(rowscale[row + r] * (1.f / DI) + 1e-5f);
        }
        #pragma unroll
        for (int t = 0; t < 4; t++) {
            const int col = n0 + wn * 64 + t * 16 + lm;
            #pragma unroll
            for (int r = 0; r < 4; r++) {
                if (OB)
                    ((ushort_t*)Cp)[(size_t)(row + r) * ldc + col] = f2bf(acc[s][t][r]);
                else
                    ((float*)Cp)[(size_t)(row + r) * ldc + col] = acc[s][t][r] * rs[r];
            }
        }
    }
}

// ---------------------------------------------------------------------------
// Depthwise causal conv (w=4) + bias + SiLU -> bf16 operand caches.
// ---------------------------------------------------------------------------
__global__ __launch_bounds__(256) void conv_silu_bf16(
    const ushort_t* __restrict__ xbcb, const float* __restrict__ cw,
    const float* __restrict__ cb, ushort_t* __restrict__ xT,
    ushort_t* __restrict__ Bn, ushort_t* __restrict__ BT,
    ushort_t* __restrict__ Cn)
{
    __shared__ ushort_t Tl[256][68];
    const int tid = threadIdx.x;
    const int c = blockIdx.x * 256 + tid;
    const int rb = blockIdx.y;
    const int row0 = rb * CONV_R;
    const bool isBC = (blockIdx.x == 8);

    const float w0 = cw[c*4+0], w1 = cw[c*4+1], w2 = cw[c*4+2], w3 = cw[c*4+3];
    const float bias = cb[c];
    float h0 = 0.f, h1 = 0.f, h2 = 0.f;
    if ((row0 & (LEN - 1)) != 0) {
        h0 = bf2f(xbcb[(size_t)(row0 - 3) * NPAD + c]);
        h1 = bf2f(xbcb[(size_t)(row0 - 2) * NPAD + c]);
        h2 = bf2f(xbcb[(size_t)(row0 - 1) * NPAD + c]);
    }
    const ushort_t* p = xbcb + (size_t)row0 * NPAD + c;
    for (int r = 0; r < CONV_R; r++) {
        float xin = bf2f(*p);
        float a = bias + w0*h0 + w1*h1 + w2*h2 + w3*xin;
        ushort_t bv = f2bf(a / (1.f + __expf(-a)));
        Tl[tid][r] = bv;
        if (isBC) {
            int row = row0 + r;
            if (tid < DS) Bn[(size_t)row * DS + tid] = bv;
            else          Cn[(size_t)row * DS + (tid - DS)] = bv;
        }
        h0 = h1; h1 = h2; h2 = xin;
        p += NPAD;
    }
    __syncthreads();

    const int seg = tid & 7;
    const int clb = tid >> 3;
    if (!isBC) {
        #pragma unroll
        for (int pass = 0; pass < 8; pass++) {
            int cl = pass * 32 + clb;
            int cc = blockIdx.x * 256 + cl;
            us8 v;
            #pragma unroll
            for (int j = 0; j < 8; j++) v[j] = Tl[cl][seg * 8 + j];
            *(us8*)&xT[(size_t)cc * NTOK + row0 + seg * 8] = v;
        }
    } else {
        #pragma unroll
        for (int pass = 0; pass < 4; pass++) {
            int n = pass * 32 + clb;
            us8 v;
            #pragma unroll
            for (int j = 0; j < 8; j++) v[j] = Tl[n][seg * 8 + j];
            *(us8*)&BT[(size_t)n * NTOK + row0 + seg * 8] = v;
        }
    }
}

// ---------------------------------------------------------------------------
// Batched head-independent GEMM: Graw[bc][t][s] = sum_n C[t,n]*B[s,n].
// ---------------------------------------------------------------------------
__global__ __launch_bounds__(256) void gct_gemm(
    const ushort_t* __restrict__ Bn, const ushort_t* __restrict__ Cn,
    float* __restrict__ Graw)
{
    const int bc = blockIdx.x;             // b*NCH + chunk
    const int chunk = bc % NCH;
    const int b = bc / NCH;
    const size_t rowbase = (size_t)b * LEN + (size_t)chunk * QCH;
    const int tid = threadIdx.x;
    const int w = tid >> 6, lane = tid & 63;
    const int lm = lane & 15, quad = lane >> 4;
    const int tw0 = w * 32;

    f32x4 acc[2][8];
    #pragma unroll
    for (int ti = 0; ti < 2; ti++)
        #pragma unroll
        for (int sj = 0; sj < 8; sj++) acc[ti][sj] = (f32x4){0.f, 0.f, 0.f, 0.f};

    #pragma unroll
    for (int ks = 0; ks < 4; ks++) {
        const int k0 = ks * 32 + quad * 8;
        bf16x8 a0 = *(const bf16x8*)&Cn[(rowbase + tw0 + lm) * DS + k0];
        bf16x8 a1 = *(const bf16x8*)&Cn[(rowbase + tw0 + 16 + lm) * DS + k0];
        #pragma unroll
        for (int sj = 0; sj < 8; sj++) {
            bf16x8 bb = *(const bf16x8*)&Bn[(rowbase + sj * 16 + lm) * DS + k0];
            acc[0][sj] = __builtin_amdgcn_mfma_f32_16x16x32_bf16(a0, bb, acc[0][sj], 0, 0, 0);
            acc[1][sj] = __builtin_amdgcn_mfma_f32_16x16x32_bf16(a1, bb, acc[1][sj], 0, 0, 0);
        }
    }
    float* G = Graw + (size_t)bc * (QCH * QCH);
    #pragma unroll
    for (int ti = 0; ti < 2; ti++)
        #pragma unroll
        for (int sj = 0; sj < 8; sj++)
            #pragma unroll
            for (int r = 0; r < 4; r++)
                G[(size_t)(tw0 + ti * 16 + quad * 4 + r) * QCH + sj * 16 + lm] = acc[ti][sj][r];
}

// ---------------------------------------------------------------------------
// dt in FULL fp32 (exp-amplified path; bf16 would random-walk csum).
// LDS-staged rewrite of the r0-r11 scalar version (was 77.6 us: 537M scalar
// global loads, issue-bound). Hl[8][1024] staged once (coalesced float4,
// broadcast reads); W slice staged per-128k chunk into padded Wl[128][36]
// (bank-conflict-free reads AND writes). Same thread->output mapping and
// SAME fp32 summation order (a0..a3 over k%4, k ascending) -> bitwise
// identical dtv/ldA to the old kernel.
// ---------------------------------------------------------------------------
__global__ __launch_bounds__(256) void dt_proc_fp32(
    const float* __restrict__ hidden, const float* __restrict__ W_in,
    const float* __restrict__ dt_bias, const float* __restrict__ A_log,
    float* __restrict__ dtv, float* __restrict__ ldA)
{
    __shared__ float Hl[8][1024];   // 32 KB
    __shared__ float Wl[128][36];   // 18 KB (+4 pad: stride 144B, 16B-aligned)
    const int tid = threadIdx.x;
    const int t0 = blockIdx.x * 8;

    // stage hidden rows t0..t0+7 (2048 float4, 8 per thread, coalesced)
    #pragma unroll
    for (int i = 0; i < 8; i++) {
        int idx = i * 256 + tid;
        int row = idx >> 8, c4 = idx & 255;
        *(float4*)&Hl[row][c4 * 4] =
            *(const float4*)&hidden[(size_t)(t0 + row) * DM + (size_t)c4 * 4];
    }

    const int h = tid & 31, tt = tid >> 5;
    float a0 = 0.f, a1 = 0.f, a2 = 0.f, a3 = 0.f;

    for (int kc = 0; kc < 8; kc++) {
        // stage W[kc*128 .. +127][TOFF..TOFF+31] (1024 float4, 4 per thread)
        #pragma unroll
        for (int i = 0; i < 4; i++) {
            int idx = i * 256 + tid;
            int row = idx >> 3, c4 = idx & 7;
            *(float4*)&Wl[row][c4 * 4] =
                *(const float4*)&W_in[(size_t)(kc * 128 + row) * DP + TOFF + c4 * 4];
        }
        __syncthreads();   // Hl (first iter) + Wl ready
        const float* hrow = &Hl[tt][kc * 128];
        #pragma unroll 8
        for (int kk = 0; kk < 128; kk += 4) {
            a0 += hrow[kk + 0] * Wl[kk + 0][h];
            a1 += hrow[kk + 1] * Wl[kk + 1][h];
            a2 += hrow[kk + 2] * Wl[kk + 2][h];
            a3 += hrow[kk + 3] * Wl[kk + 3][h];
        }
        __syncthreads();   // all reads done before next Wl overwrite
    }

    float v = (a0 + a1) + (a2 + a3) + dt_bias[h];
    float sp = (v > 20.f) ? v : log1pf(expf(v));
    int idx = (t0 + tt) * NH + h;
    dtv[idx] = sp;
    ldA[idx] = -sp * expf(A_log[h]);
}

// ---------------------------------------------------------------------------
// Per-(b,h,chunk) prefix scan of ldA (one wave per block, shfl-based).
// ---------------------------------------------------------------------------
__global__ __launch_bounds__(64) void scan_chunk(
    const float* __restrict__ dtv, const float* __restrict__ ldA,
    float* __restrict__ lcpb, float* __restrict__ dtsb,
    float* __restrict__ coefb, float* __restrict__ csum)
{
    const int blk = blockIdx.x;            // bh*NCH + chunk
    const int chunk = blk % NCH;
    const int bh = blk / NCH;
    const int h = bh % NH;
    const int b = bh / NH;
    const int lane = threadIdx.x;
    const size_t rowbase = (size_t)b * LEN + (size_t)chunk * QCH;
    const int t0 = 2 * lane, t1 = 2 * lane + 1;
    float v0 = ldA[(rowbase + t0) * NH + h];
    float v1 = ldA[(rowbase + t1) * NH + h];
    float d0 = dtv[(rowbase + t0) * NH + h];
    float d1 = dtv[(rowbase + t1) * NH + h];
    float pair = v0 + v1;
    #pragma unroll
    for (int off = 1; off < 64; off <<= 1) {
        float n = __shfl_up(pair, off, 64);
        if (lane >= off) pair += n;
    }
    float l1 = pair, l0 = pair - v1;
    float total = __shfl(pair, 63, 64);
    size_t base = (size_t)blk * QCH;
    *(float2*)&lcpb[base + t0] = make_float2(l0, l1);
    *(float2*)&dtsb[base + t0] = make_float2(d0, d1);
    *(float2*)&coefb[base + t0] =
        make_float2(__expf(total - l0) * d0, __expf(total - l1) * d1);
    if (lane == 63) csum[blk] = total;
}

// ---------------------------------------------------------------------------
// FUSED Phase 1+2 (r9-measured config: 256 blocks, nhalf split; all 4 waves
// of a block share the same 64 xT rows via L1 -> no read replication).
// ---------------------------------------------------------------------------
__global__ __launch_bounds__(256) void phase12_fused(
    const ushort_t* __restrict__ xT, const ushort_t* __restrict__ BT,
    const float* __restrict__ coefb, const float* __restrict__ csum,
    ushort_t* __restrict__ hsb)
{
    const int blk = blockIdx.x;            // (b*NH + h)*2 + nhalf
    const int nhalf = blk & 1;
    const int bh = blk >> 1;
    const int h = bh & (NH - 1);
    const int b = bh >> 5;
    const int tid = threadIdx.x;
    const int w = tid >> 6, lane = tid & 63;
    const int lm = lane & 15, quad = lane >> 4;
    const int nw0 = nhalf * 64 + w * 16;   // 16 n-cols per wave

    f32x4 run[4];
    #pragma unroll
    for (int mi = 0; mi < 4; mi++) run[mi] = (f32x4){0.f, 0.f, 0.f, 0.f};

    for (int c = 0; c < NCH; c++) {
        const size_t rowbase = (size_t)b * LEN + (size_t)c * QCH;
        const size_t cb = ((size_t)bh * NCH + c) * QCH;
        const float P = __expf(csum[bh * NCH + c]);

        f32x4 acc[4];
        #pragma unroll
        for (int mi = 0; mi < 4; mi++) acc[mi] = (f32x4){0.f, 0.f, 0.f, 0.f};

        #pragma unroll
        for (int ks = 0; ks < 4; ks++) {
            const int k0 = ks * 32 + quad * 8;
            bf16x8 a[4];
            #pragma unroll
            for (int mi = 0; mi < 4; mi++)
                a[mi] = *(const bf16x8*)&xT[(size_t)(h * HD + mi * 16 + lm) * NTOK + rowbase + k0];
            float4 c0 = *(const float4*)&coefb[cb + k0];
            float4 c1 = *(const float4*)&coefb[cb + k0 + 4];
            float cf[8] = { c0.x, c0.y, c0.z, c0.w, c1.x, c1.y, c1.z, c1.w };
            us8 raw = *(const us8*)&BT[(size_t)(nw0 + lm) * NTOK + rowbase + k0];
            us8 sb;
            #pragma unroll
            for (int j = 0; j < 8; j++) sb[j] = f2bf(bf2f(raw[j]) * cf[j]);
            bf16x8 bfr = us2bf(sb);
            __builtin_amdgcn_s_setprio(1);
            #pragma unroll
            for (int mi = 0; mi < 4; mi++)
                acc[mi] = __builtin_amdgcn_mfma_f32_16x16x32_bf16(a[mi], bfr, acc[mi], 0, 0, 0);
            __builtin_amdgcn_s_setprio(0);
        }

        // write h_start (pre-update run), then recurrence update
        ushort_t* hb = hsb + ((size_t)bh * NCH + c) * (HD * DS);
        #pragma unroll
        for (int mi = 0; mi < 4; mi++)
            #pragma unroll
            for (int r = 0; r < 4; r++)
                hb[(size_t)(mi * 16 + quad * 4 + r) * DS + nw0 + lm] = f2bf(run[mi][r]);
        #pragma unroll
        for (int mi = 0; mi < 4; mi++)
            #pragma unroll
            for (int r = 0; r < 4; r++)
                run[mi][r] = P * run[mi][r] + acc[mi][r];
    }
}

// ---------------------------------------------------------------------------
// Phase 3 (MFMA) + FUSED GATE: Y = G@X + Chat@hs^T; epilogue adds D*x,
// multiplies silu(z) (gate), writes gated bf16 v into zxb's dead xBC slice
// (cols DI.., ld=NPAD) and accumulates per-token sum(v^2) via atomics.
// ---------------------------------------------------------------------------
__global__ __launch_bounds__(256) void phase3_mfma(
    const ushort_t* __restrict__ xT, const ushort_t* __restrict__ Cn,
    const ushort_t* __restrict__ hsb, const float* __restrict__ Graw,
    const float* __restrict__ lcpb, const float* __restrict__ dtsb,
    const float* __restrict__ Dvec, ushort_t* __restrict__ zxb,
    float* __restrict__ ss)
{
    const int tid = threadIdx.x;
    const int h = blockIdx.x & (NH - 1);
    const int bc = blockIdx.x >> 5;        // b*NCH + chunk
    const int chunk = bc % NCH;
    const int b = bc / NCH;
    const int blko = (b * NH + h) * NCH + chunk;
    const size_t rowbase = (size_t)b * LEN + (size_t)chunk * QCH;

    __shared__ float lcp[QCH];
    __shared__ float dts[QCH];
    if (tid < QCH) {
        lcp[tid] = lcpb[(size_t)blko * QCH + tid];
        dts[tid] = dtsb[(size_t)blko * QCH + tid];
    }
    __syncthreads();

    const int w = tid >> 6, lane = tid & 63;
    const int lm = lane & 15, quad = lane >> 4;
    const int tw0 = w * 32;

    const float* Gr = Graw + (size_t)bc * (QCH * QCH);
    const ushort_t* hsp = hsb + (size_t)blko * (HD * DS);

    f32x4 acc2[2][4];
    #pragma unroll
    for (int ti = 0; ti < 2; ti++)
        #pragma unroll
        for (int pi = 0; pi < 4; pi++) acc2[ti][pi] = (f32x4){0.f, 0.f, 0.f, 0.f};

    #pragma unroll
    for (int ks = 0; ks < 8; ks++) {
        bf16x8 a[2], bb[4];
        if (ks < 4) {
            const int k0 = ks * 32 + quad * 8;
            #pragma unroll
            for (int ti = 0; ti < 2; ti++) {
                int t = tw0 + ti * 16 + lm;
                float lt = lcp[t];
                const float* gp = Gr + (size_t)t * QCH + k0;
                float4 g0 = *(const float4*)gp;
                float4 g1 = *(const float4*)(gp + 4);
                float ge[8] = { g0.x, g0.y, g0.z, g0.w, g1.x, g1.y, g1.z, g1.w };
                us8 sb;
                #pragma unroll
                for (int j = 0; j < 8; j++) {
                    int s = k0 + j;
                    float wv = (s <= t) ? (__expf(lt - lcp[s]) * dts[s]) : 0.f;
                    sb[j] = f2bf(ge[j] * wv);
                }
                a[ti] = us2bf(sb);
            }
            #pragma unroll
            for (int pi = 0; pi < 4; pi++)
                bb[pi] = *(const bf16x8*)&xT[(size_t)(h * HD + pi * 16 + lm) * NTOK + rowbase + k0];
        } else {
            const int k0 = (ks - 4) * 32 + quad * 8;
            #pragma unroll
            for (int ti = 0; ti < 2; ti++) {
                int t = tw0 + ti * 16 + lm;
                float sc = __expf(lcp[t]);
                us8 raw = *(const us8*)&Cn[(rowbase + t) * DS + k0];
                us8 sb;
                #pragma unroll
                for (int j = 0; j < 8; j++) sb[j] = f2bf(bf2f(raw[j]) * sc);
                a[ti] = us2bf(sb);
            }
            #pragma unroll
            for (int pi = 0; pi < 4; pi++)
                bb[pi] = *(const bf16x8*)&hsp[(size_t)(pi * 16 + lm) * DS + k0];
        }
        __builtin_amdgcn_s_setprio(1);
        #pragma unroll
        for (int ti = 0; ti < 2; ti++)
            #pragma unroll
            for (int pi = 0; pi < 4; pi++)
                acc2[ti][pi] = __builtin_amdgcn_mfma_f32_16x16x32_bf16(a[ti], bb[pi], acc2[ti][pi], 0, 0, 0);
        __builtin_amdgcn_s_setprio(0);
    }

    const float Dh = Dvec[h];
    float vsq[2][4] = {};
    #pragma unroll
    for (int ti = 0; ti < 2; ti++)
        #pragma unroll
        for (int pi = 0; pi < 4; pi++) {
            int tb = tw0 + ti * 16 + quad * 4;
            int col = h * HD + pi * 16 + lm;
            ushort4 xv = *(const ushort4*)&xT[(size_t)(h * HD + pi * 16 + lm) * NTOK + rowbase + tb];
            const ushort_t* xe = (const ushort_t*)&xv;
            #pragma unroll
            for (int r = 0; r < 4; r++) {
                size_t grow = rowbase + tb + r;
                float y = acc2[ti][pi][r] + Dh * bf2f(xe[r]);
                float z = bf2f(zxb[grow * NPAD + col]);
                float v = y * (z / (1.f + __expf(-z)));
                vsq[ti][r] += v * v;
                zxb[grow * NPAD + DI + col] = f2bf(v);
            }
        }
    #pragma unroll
    for (int ti = 0; ti < 2; ti++)
        #pragma unroll
        for (int r = 0; r < 4; r++) {
            float s = vsq[ti][r];
            s += __shfl_xor(s, 1, 64);
            s += __shfl_xor(s, 2, 64);
            s += __shfl_xor(s, 4, 64);
            s += __shfl_xor(s, 8, 64);
            if (lm == 0) {
                int tb = tw0 + ti * 16 + quad * 4 + r;
                atomicAdd(&ss[rowbase + tb], s);
            }
        }
}

// ---------------------------------------------------------------------------
extern "C" void kernel_launch(void* const* d_in, const int* in_sizes, int n_in,
                              void* d_out, int out_size, void* d_ws, size_t ws_size,
                              hipStream_t stream)
{
    const float* hidden  = (const float*)d_in[0];
    const float* W_in    = (const float*)d_in[1];
    const float* conv_w  = (const float*)d_in[2];
    const float* conv_b  = (const float*)d_in[3];
    const float* dt_bias = (const float*)d_in[4];
    const float* A_log   = (const float*)d_in[5];
    const float* Dv      = (const float*)d_in[6];
    const float* norm_w  = (const float*)d_in[7];
    const float* W_out   = (const float*)d_in[8];
    float* out = (float*)d_out;

    char* ws = (char*)d_ws;
    size_t o = 0;
    ushort_t* zxb  = (ushort_t*)(ws + o); o += (size_t)NTOK * NPAD * 2;             // 71.3 MB
    float* S       = (float*)(ws + o);    o += (size_t)BSZ * NH * NCH * HD * DS * 4;// 67.1 MB (Ah/W1t alias region)
    ushort_t* xT   = (ushort_t*)(ws + o); o += (size_t)DI * NTOK * 2;               // 33.6 MB
    ushort_t* Bn   = (ushort_t*)(ws + o); o += (size_t)NTOK * DS * 2;               // 2.1 MB
    ushort_t* BT   = (ushort_t*)(ws + o); o += (size_t)DS * NTOK * 2;               // 2.1 MB
    ushort_t* Cn   = (ushort_t*)(ws + o); o += (size_t)NTOK * DS * 2;               // 2.1 MB
    ushort_t* hsb  = (ushort_t*)(ws + o); o += (size_t)BSZ * NH * NCH * HD * DS * 2;// 33.6 MB
    float* Graw    = (float*)(ws + o);    o += (size_t)BSZ * NCH * QCH * QCH * 4;   // 4.2 MB
    float* dtv     = (float*)(ws + o);    o += (size_t)NTOK * NH * 4;
    float* ldA     = (float*)(ws + o);    o += (size_t)NTOK * NH * 4;
    float* lcpb    = (float*)(ws + o);    o += (size_t)BSZ * NH * LEN * 4;
    float* dtsb    = (float*)(ws + o);    o += (size_t)BSZ * NH * LEN * 4;
    float* coefb   = (float*)(ws + o);    o += (size_t)BSZ * NH * LEN * 4;
    float* csum    = (float*)(ws + o);    o += (size_t)BSZ * NH * NCH * 4;
    float* ss      = (float*)(ws + o);    o += (size_t)NTOK * 4;
    (void)S;
    // Aliases (dead-region reuse):
    ushort_t* Ah   = (ushort_t*)S;                                   // GEMM1 A (bf16 hidden)
    ushort_t* W1t  = (ushort_t*)((char*)S + (size_t)NTOK * DM * 2);  // GEMM1 B^T
    ushort_t* Wot  = hsb;                                            // post-phase3 (hsb dead)
    ushort_t* xbcb = zxb + DI;                                       // xBC slice, ld=NPAD
    ushort_t* ynb  = zxb + DI;                                       // gated-v slice (post-conv), ld=NPAD

    // 0) zero the sum-of-squares accumulator (consumed by phase3 atomics)
    hipMemsetAsync(ss, 0, (size_t)NTOK * 4, stream);
    // 1) bf16 conversions for GEMM1
    cvt_bf16<<<(NTOK * DM) / 1024, 256, 0, stream>>>(hidden, Ah);
    transpose_cvt<<<dim3(NPAD / 32, DM / 32), 256, 0, stream>>>(
        W_in, W1t, nullptr, DM, NPAD, DP);
    // 2) GEMM1 (merged z + xBC, bf16 out) — r8 kernel, split into two M-half
    //    dispatches (~51 us each) so sub-51us kernels surface in the top-5.
    gemm1_tb<<<dim3(NPAD / 128, NTOK / 256), 256, 0, stream>>>(
        Ah, W1t, zxb, DM, DM, DM, NPAD);
    gemm1_tb<<<dim3(NPAD / 128, NTOK / 256), 256, 0, stream>>>(
        Ah + (size_t)(NTOK / 2) * DM, W1t,
        zxb + (size_t)(NTOK / 2) * NPAD, DM, DM, DM, NPAD);
    // 3) conv + SiLU -> bf16 operand caches
    conv_silu_bf16<<<dim3(CD / 256, NRB), 256, 0, stream>>>(
        xbcb, conv_w, conv_b, xT, Bn, BT, Cn);
    // 4) head-shared C.B^T (once per (b,chunk))
    gct_gemm<<<BSZ * NCH, 256, 0, stream>>>(Bn, Cn, Graw);
    // 5) dt in fp32 (LDS-staged rewrite; was 77.6 us issue-bound) + scan
    dt_proc_fp32<<<NTOK / 8, 256, 0, stream>>>(hidden, W_in, dt_bias, A_log, dtv, ldA);
    scan_chunk<<<BSZ * NH * NCH, 64, 0, stream>>>(dtv, ldA, lcpb, dtsb, coefb, csum);
    // 6+7) FUSED chunk states + cross-chunk recurrence -> bf16 h_start.
    phase12_fused<<<BSZ * NH * 2, 256, 0, stream>>>(xT, BT, coefb, csum, hsb);
    // 8) per-chunk outputs + fused gate -> gated bf16 v into zxb xBC slice,
    //    per-token sum(v^2) via atomics
    phase3_mfma<<<BSZ * NH * NCH, 256, 0, stream>>>(
        xT, Cn, hsb, Graw, lcpb, dtsb, Dv, zxb, ss);
    // 9) W_out transpose (hsb dead) with norm_w folded in, then
    //    out = (v @ diag(nw) W_out) * rsqrt(ss/DI+eps)  (RMS fused in epilogue)
    transpose_cvt<<<dim3(DM / 32, DI / 32), 256, 0, stream>>>(
        W_out, Wot, norm_w, DI, DM, DM);
    gemm128<false><<<dim3(DM / 128, NTOK / 128), 256, 0, stream>>>(
        ynb, Wot, out, ss, DI, NPAD, DI, DM);
}